// Round 6
// baseline (200.234 us; speedup 1.0000x reference)
//
#include <hip/hip_runtime.h>
#include <hip/hip_bf16.h>

typedef __bf16 bf16;
typedef __bf16 bf16x8 __attribute__((ext_vector_type(8)));
typedef __bf16 bf16x4 __attribute__((ext_vector_type(4)));
typedef float  f32x4  __attribute__((ext_vector_type(4)));
typedef float  f32x2  __attribute__((ext_vector_type(2)));

#define NB    2
#define CCH   256
#define NPIX  2304
#define WIMG  48
// scale * log2(e) = (1/sqrt(32)) * 1.4426950408889634  (folded into Kt)
#define SLOG2E 0.25503487f
#define NSPLIT 2
#define KHALF  1152
#define TK     128
#define NITER  9

// ---------------------------------------------------------------------------
// Kernel 1: qkv = w_qkv @ x   (M=768, K=256, cols = B*2304)
// Qt/Kt as [bh][n][32] bf16 (token-major; Kt pre-scaled by scale*log2e),
// V as [bh][32][n] bf16.
// ---------------------------------------------------------------------------
__global__ __launch_bounds__(256) void qkv_gemm(const float* __restrict__ x,
                                                const float* __restrict__ w,
                                                bf16* __restrict__ Qt,
                                                bf16* __restrict__ Kt,
                                                bf16* __restrict__ Vb) {
    __shared__ __align__(16) bf16 xT[64][40];   // [n][c] transposed tile, padded
    const int tid  = threadIdx.x;
    const int lane = tid & 63;
    const int wv   = tid >> 6;
    const int wn   = wv & 1, wo = wv >> 1;
    const int l15  = lane & 15, l4 = lane >> 4;
    const int g0 = blockIdx.x * 64;
    const int b  = g0 / NPIX;
    const int n0 = g0 % NPIX;
    const int o0 = blockIdx.y * 64;
    const float* xb = x + (size_t)b * CCH * NPIX;

    f32x4 acc[2][2] = {};

    for (int kc = 0; kc < 8; ++kc) {
        const int c0 = kc * 32;
        for (int r = 0; r < 8; ++r) {
            int idx = r * 256 + tid;
            int c = idx >> 6, n = idx & 63;
            xT[n][c] = (bf16)xb[(size_t)(c0 + c) * NPIX + n0 + n];
        }
        __syncthreads();
        bf16x8 afr[2], bfr[2];
        for (int at = 0; at < 2; ++at) {
            const float* wp = w + (size_t)(o0 + wo * 32 + at * 16 + l15) * CCH + c0 + l4 * 8;
            f32x4 w0 = *(const f32x4*)wp;
            f32x4 w1 = *(const f32x4*)(wp + 4);
            bf16x8 a;
            for (int i = 0; i < 4; ++i) { a[i] = (bf16)w0[i]; a[i + 4] = (bf16)w1[i]; }
            afr[at] = a;
        }
        for (int bt = 0; bt < 2; ++bt)
            bfr[bt] = *(const bf16x8*)&xT[wn * 32 + bt * 16 + l15][l4 * 8];
        for (int at = 0; at < 2; ++at)
            for (int bt = 0; bt < 2; ++bt)
                acc[at][bt] = __builtin_amdgcn_mfma_f32_16x16x32_bf16(afr[at], bfr[bt],
                                                                     acc[at][bt], 0, 0, 0);
        __syncthreads();
    }

    for (int at = 0; at < 2; ++at) {
        const int otile = o0 + wo * 32 + at * 16;
        const int h    = otile / 96;
        const int role = (otile % 96) / 32;            // 0=q 1=k 2=v
        const int ddb  = (otile % 32) + l4 * 4;
        const int bh   = b * 8 + h;
        for (int bt = 0; bt < 2; ++bt) {
            const int n = n0 + wn * 32 + bt * 16 + l15;
            if (role == 2) {
                for (int r = 0; r < 4; ++r)
                    Vb[(size_t)(bh * 32 + ddb + r) * NPIX + n] = (bf16)acc[at][bt][r];
            } else if (role == 1) {
                bf16x4 pk;
                for (int r = 0; r < 4; ++r) pk[r] = (bf16)(acc[at][bt][r] * SLOG2E);
                *(bf16x4*)&Kt[((size_t)bh * NPIX + n) * 32 + ddb] = pk;
            } else {
                bf16x4 pk;
                for (int r = 0; r < 4; ++r) pk[r] = (bf16)acc[at][bt][r];
                *(bf16x4*)&Qt[((size_t)bh * NPIX + n) * 32 + ddb] = pk;
            }
        }
    }
}

// ---------------------------------------------------------------------------
// Kernel 2: flash attention, K-split x2, BARRIER-FREE.
// K/V (4.7 MB total) are L2/L3-resident: MFMA A-fragments are loaded straight
// from global (the K frag is a contiguous 1KB/wave read). Only P goes through
// LDS (wave-private rows, same-wave DS ordering -> no __syncthreads at all).
// ---------------------------------------------------------------------------
__global__ __launch_bounds__(256, 4) void attn_kernel(const bf16* __restrict__ Qt,
                                                      const bf16* __restrict__ Kt,
                                                      const bf16* __restrict__ Vb,
                                                      float* __restrict__ Opart,
                                                      float* __restrict__ MLpart) {
    __shared__ __align__(16) bf16 Ptile[64][136];   // [q][k] wave-private rows
    const int tid  = threadIdx.x;
    const int lane = tid & 63;
    const int wv   = tid >> 6;
    const int l15  = lane & 15, l4 = lane >> 4;
    const int bh    = blockIdx.y;
    const int split = blockIdx.z;
    const int q0 = blockIdx.x * 64;
    const int q  = q0 + wv * 16 + l15;

    const bf16* Kbh = Kt + (size_t)bh * NPIX * 32 + (size_t)split * KHALF * 32;
    const bf16* Vbh = Vb + (size_t)bh * 32 * NPIX + split * KHALF;

    // Q fragment: B[k=d][col=q], lane holds d = l4*8..+7 for its q column
    bf16x8 qf = *(const bf16x8*)&Qt[((size_t)bh * NPIX + q) * 32 + l4 * 8];

    f32x4 O0 = {}, O1 = {};
    float m_run = -INFINITY, l_run = 0.f;
    const int qrow = wv * 16 + l15;

    for (int kt = 0; kt < NITER; ++kt) {
        const int k0 = kt * TK;

        // S = K^T Q; A-frag read straight from global (L2-hot, 1KB/wave contiguous)
        f32x4 s[8];
        for (int rt = 0; rt < 8; ++rt) {
            bf16x8 a = *(const bf16x8*)&Kbh[(size_t)(k0 + rt * 16 + l15) * 32 + l4 * 8];
            f32x4 z = {};
            s[rt] = __builtin_amdgcn_mfma_f32_16x16x32_bf16(a, qf, z, 0, 0, 0);
        }

        // online softmax over key dim (column q = lanes {l, l^16, l^32, l^48})
        float tmax = -INFINITY;
        for (int rt = 0; rt < 8; ++rt)
            for (int r = 0; r < 4; ++r) tmax = fmaxf(tmax, s[rt][r]);
        tmax = fmaxf(tmax, __shfl_xor(tmax, 16));
        tmax = fmaxf(tmax, __shfl_xor(tmax, 32));
        const float m_new = fmaxf(m_run, tmax);
        const float f = __builtin_amdgcn_exp2f(m_run - m_new);
        float psum = 0.f;
        for (int rt = 0; rt < 8; ++rt) {
            bf16x4 pk;
            for (int r = 0; r < 4; ++r) {
                float p = __builtin_amdgcn_exp2f(s[rt][r] - m_new);
                psum += p;
                pk[r] = (bf16)p;
            }
            *(bf16x4*)&Ptile[qrow][rt * 16 + l4 * 4] = pk;
        }
        psum += __shfl_xor(psum, 16);
        psum += __shfl_xor(psum, 32);
        l_run = l_run * f + psum;
        m_run = m_new;
        for (int i = 0; i < 4; ++i) { O0[i] *= f; O1[i] *= f; }

        // O += V * P  (A = V rows from global, B = P cols q); 4 k-chunks of 32
        for (int ks = 0; ks < 4; ++ks) {
            bf16x8 pb = *(const bf16x8*)&Ptile[qrow][ks * 32 + l4 * 8];
            bf16x8 v0 = *(const bf16x8*)&Vbh[(size_t)l15 * NPIX + k0 + ks * 32 + l4 * 8];
            bf16x8 v1 = *(const bf16x8*)&Vbh[(size_t)(16 + l15) * NPIX + k0 + ks * 32 + l4 * 8];
            O0 = __builtin_amdgcn_mfma_f32_16x16x32_bf16(v0, pb, O0, 0, 0, 0);
            O1 = __builtin_amdgcn_mfma_f32_16x16x32_bf16(v1, pb, O1, 0, 0, 0);
        }
        // no barriers: Ptile rows are wave-private; K/V come from cache
    }

    // store unnormalized partials
    f32x4* Op4 = (f32x4*)(Opart + ((size_t)(split * 16 + bh) * NPIX + q) * 32);
    Op4[l4]     = O0;   // d = l4*4 + r
    Op4[4 + l4] = O1;   // d = 16 + l4*4 + r
    if (l4 == 0) {
        f32x2 ml; ml[0] = m_run; ml[1] = l_run;
        *(f32x2*)&MLpart[((size_t)(split * 16 + bh) * NPIX + q) * 2] = ml;
    }
}

// ---------------------------------------------------------------------------
// Kernel 2b: fused epilogue — combine K-split partials + lepe (dw 3x3 + bias)
// Writes aout bf16 [c][n].  Grid (36, 16), 256 threads.
// Thread t: channel d = t>>3 of head bh, 8 consecutive q starting (t&7)*8.
// ---------------------------------------------------------------------------
__global__ __launch_bounds__(256) void epilogue_kernel(const float* __restrict__ Opart,
                                                       const float* __restrict__ MLpart,
                                                       const bf16* __restrict__ Vb,
                                                       const float* __restrict__ wl,
                                                       const float* __restrict__ bl,
                                                       bf16* __restrict__ aout) {
    const int tid = threadIdx.x;
    const int bh  = blockIdx.y;
    const int q0  = blockIdx.x * 64;
    const int d   = tid >> 3;              // 0..31
    const int n8  = (tid & 7) * 8;         // 8 q per thread
    const int c   = bh * 32 + d;           // row in aout / Vb  (= b*256 + ch)
    const int ch  = c & 255;               // weight channel
    const float bias = bl[ch];
    float wgt[9];
    for (int i = 0; i < 9; ++i) wgt[i] = wl[ch * 9 + i];
    const bf16* vrow = Vb + (size_t)c * NPIX;

    for (int j = 0; j < 8; ++j) {
        const int q = q0 + n8 + j;
        // combine the two split partials
        f32x2 ml0 = *(const f32x2*)&MLpart[((size_t)bh * NPIX + q) * 2];
        f32x2 ml1 = *(const f32x2*)&MLpart[((size_t)(16 + bh) * NPIX + q) * 2];
        const float m  = fmaxf(ml0[0], ml1[0]);
        const float w0 = __builtin_amdgcn_exp2f(ml0[0] - m);
        const float w1 = __builtin_amdgcn_exp2f(ml1[0] - m);
        const float inv = 1.f / (w0 * ml0[1] + w1 * ml1[1]);
        const float o0 = Opart[((size_t)bh * NPIX + q) * 32 + d];
        const float o1 = Opart[((size_t)(16 + bh) * NPIX + q) * 32 + d];
        float val = (w0 * o0 + w1 * o1) * inv;
        // lepe: depthwise 3x3 over the 48x48 image, channel c
        const int y = q / WIMG, xx = q % WIMG;
        float acc = bias;
        for (int dy = -1; dy <= 1; ++dy) {
            const int yy = y + dy;
            if (yy < 0 || yy >= WIMG) continue;
            for (int dx = -1; dx <= 1; ++dx) {
                const int xc = xx + dx;
                if (xc < 0 || xc >= WIMG) continue;
                acc += (float)vrow[yy * WIMG + xc] * wgt[(dy + 1) * 3 + dx + 1];
            }
        }
        aout[(size_t)c * NPIX + q] = (bf16)(val + acc);
    }
}

// ---------------------------------------------------------------------------
// Kernel 4: out = w_proj @ attn_out + b_proj  (fp32 output)
// ---------------------------------------------------------------------------
__global__ __launch_bounds__(256) void proj_gemm(const bf16* __restrict__ ain,
                                                 const float* __restrict__ w,
                                                 const float* __restrict__ bp,
                                                 float* __restrict__ out) {
    __shared__ __align__(16) bf16 aT[64][40];
    const int tid  = threadIdx.x;
    const int lane = tid & 63;
    const int wv   = tid >> 6;
    const int wn   = wv & 1, wo = wv >> 1;
    const int l15  = lane & 15, l4 = lane >> 4;
    const int g0 = blockIdx.x * 64;
    const int b  = g0 / NPIX;
    const int n0 = g0 % NPIX;
    const int o0 = blockIdx.y * 64;
    const bf16* ab = ain + (size_t)b * CCH * NPIX;

    f32x4 acc[2][2] = {};
    for (int kc = 0; kc < 8; ++kc) {
        const int c0 = kc * 32;
        for (int r = 0; r < 8; ++r) {
            int idx = r * 256 + tid;
            int ci = idx >> 6, n = idx & 63;
            aT[n][ci] = ab[(size_t)(c0 + ci) * NPIX + n0 + n];
        }
        __syncthreads();
        bf16x8 afr[2], bfr[2];
        for (int at = 0; at < 2; ++at) {
            const float* wp = w + (size_t)(o0 + wo * 32 + at * 16 + l15) * CCH + c0 + l4 * 8;
            f32x4 w0 = *(const f32x4*)wp;
            f32x4 w1 = *(const f32x4*)(wp + 4);
            bf16x8 a;
            for (int i = 0; i < 4; ++i) { a[i] = (bf16)w0[i]; a[i + 4] = (bf16)w1[i]; }
            afr[at] = a;
        }
        for (int bt = 0; bt < 2; ++bt)
            bfr[bt] = *(const bf16x8*)&aT[wn * 32 + bt * 16 + l15][l4 * 8];
        for (int at = 0; at < 2; ++at)
            for (int bt = 0; bt < 2; ++bt)
                acc[at][bt] = __builtin_amdgcn_mfma_f32_16x16x32_bf16(afr[at], bfr[bt],
                                                                     acc[at][bt], 0, 0, 0);
        __syncthreads();
    }
    for (int at = 0; at < 2; ++at)
        for (int bt = 0; bt < 2; ++bt) {
            const int n = n0 + wn * 32 + bt * 16 + l15;
            for (int r = 0; r < 4; ++r) {
                const int o = o0 + wo * 32 + at * 16 + l4 * 4 + r;
                out[(size_t)(b * 256 + o) * NPIX + n] = acc[at][bt][r] + bp[o];
            }
        }
}

// ---------------------------------------------------------------------------
extern "C" void kernel_launch(void* const* d_in, const int* in_sizes, int n_in,
                              void* d_out, int out_size, void* d_ws, size_t ws_size,
                              hipStream_t stream) {
    const float* x      = (const float*)d_in[0];
    const float* w_qkv  = (const float*)d_in[1];
    const float* w_lepe = (const float*)d_in[2];
    const float* b_lepe = (const float*)d_in[3];
    const float* w_proj = (const float*)d_in[4];
    const float* b_proj = (const float*)d_in[5];
    float* out = (float*)d_out;

    // ws layout: Qt|Kt|V|aout (bf16, 4 x 1179648 elems = 9.44MB),
    // then Opart fp32 (2*16*2304*32 = 9.44MB), MLpart fp32 (0.59MB)
    bf16* Qt   = (bf16*)d_ws;
    bf16* Kt   = Qt + 1179648;
    bf16* Vb   = Kt + 1179648;
    bf16* aout = Vb + 1179648;
    float* Opart  = (float*)((char*)d_ws + 9437184);
    float* MLpart = Opart + 2359296;

    qkv_gemm      <<<dim3(72, 12),    256, 0, stream>>>(x, w_qkv, Qt, Kt, Vb);
    attn_kernel   <<<dim3(36, 16, 2), 256, 0, stream>>>(Qt, Kt, Vb, Opart, MLpart);
    epilogue_kernel<<<dim3(36, 16),   256, 0, stream>>>(Opart, MLpart, Vb, w_lepe, b_lepe, aout);
    proj_gemm     <<<dim3(72, 4),     256, 0, stream>>>(aout, w_proj, b_proj, out);
}

// Round 10
// 169.611 us; speedup vs baseline: 1.1806x; 1.1806x over previous
//
#include <hip/hip_runtime.h>
#include <hip/hip_bf16.h>

typedef __bf16 bf16;
typedef __bf16 bf16x8 __attribute__((ext_vector_type(8)));
typedef __bf16 bf16x4 __attribute__((ext_vector_type(4)));
typedef float  f32x4  __attribute__((ext_vector_type(4)));
typedef float  f32x2  __attribute__((ext_vector_type(2)));

#define NB    2
#define CCH   256
#define NPIX  2304
#define WIMG  48
// scale * log2(e) = (1/sqrt(32)) * 1.4426950408889634  (folded into Kt)
#define SLOG2E 0.25503487f
#define NSPLIT 2
#define KHALF  1152
#define TK     128
#define NITER  9

// ---------------------------------------------------------------------------
// Kernel 1: qkv = w_qkv @ x   (M=768, K=256, cols = B*2304)
// Qt/Kt as [bh][n][32] bf16 (token-major; Kt pre-scaled by scale*log2e),
// V as [bh][32][n] bf16.
// ---------------------------------------------------------------------------
__global__ __launch_bounds__(256) void qkv_gemm(const float* __restrict__ x,
                                                const float* __restrict__ w,
                                                bf16* __restrict__ Qt,
                                                bf16* __restrict__ Kt,
                                                bf16* __restrict__ Vb) {
    __shared__ __align__(16) bf16 xT[64][40];   // [n][c] transposed tile, padded
    const int tid  = threadIdx.x;
    const int lane = tid & 63;
    const int wv   = tid >> 6;
    const int wn   = wv & 1, wo = wv >> 1;
    const int l15  = lane & 15, l4 = lane >> 4;
    const int g0 = blockIdx.x * 64;
    const int b  = g0 / NPIX;
    const int n0 = g0 % NPIX;
    const int o0 = blockIdx.y * 64;
    const float* xb = x + (size_t)b * CCH * NPIX;

    f32x4 acc[2][2] = {};

    for (int kc = 0; kc < 8; ++kc) {
        const int c0 = kc * 32;
        for (int r = 0; r < 8; ++r) {
            int idx = r * 256 + tid;
            int c = idx >> 6, n = idx & 63;
            xT[n][c] = (bf16)xb[(size_t)(c0 + c) * NPIX + n0 + n];
        }
        __syncthreads();
        bf16x8 afr[2], bfr[2];
        for (int at = 0; at < 2; ++at) {
            const float* wp = w + (size_t)(o0 + wo * 32 + at * 16 + l15) * CCH + c0 + l4 * 8;
            f32x4 w0 = *(const f32x4*)wp;
            f32x4 w1 = *(const f32x4*)(wp + 4);
            bf16x8 a;
            for (int i = 0; i < 4; ++i) { a[i] = (bf16)w0[i]; a[i + 4] = (bf16)w1[i]; }
            afr[at] = a;
        }
        for (int bt = 0; bt < 2; ++bt)
            bfr[bt] = *(const bf16x8*)&xT[wn * 32 + bt * 16 + l15][l4 * 8];
        for (int at = 0; at < 2; ++at)
            for (int bt = 0; bt < 2; ++bt)
                acc[at][bt] = __builtin_amdgcn_mfma_f32_16x16x32_bf16(afr[at], bfr[bt],
                                                                     acc[at][bt], 0, 0, 0);
        __syncthreads();
    }

    for (int at = 0; at < 2; ++at) {
        const int otile = o0 + wo * 32 + at * 16;
        const int h    = otile / 96;
        const int role = (otile % 96) / 32;            // 0=q 1=k 2=v
        const int ddb  = (otile % 32) + l4 * 4;
        const int bh   = b * 8 + h;
        for (int bt = 0; bt < 2; ++bt) {
            const int n = n0 + wn * 32 + bt * 16 + l15;
            if (role == 2) {
                for (int r = 0; r < 4; ++r)
                    Vb[(size_t)(bh * 32 + ddb + r) * NPIX + n] = (bf16)acc[at][bt][r];
            } else if (role == 1) {
                bf16x4 pk;
                for (int r = 0; r < 4; ++r) pk[r] = (bf16)(acc[at][bt][r] * SLOG2E);
                *(bf16x4*)&Kt[((size_t)bh * NPIX + n) * 32 + ddb] = pk;
            } else {
                bf16x4 pk;
                for (int r = 0; r < 4; ++r) pk[r] = (bf16)acc[at][bt][r];
                *(bf16x4*)&Qt[((size_t)bh * NPIX + n) * 32 + ddb] = pk;
            }
        }
    }
}

// ---------------------------------------------------------------------------
// Kernel 2: flash attention, K-split x2 (flash-decoding). Grid (36, 16, 2).
// Tk=128, 9 iters/block, LDS-staged K/V with register-prefetch double buffer
// (r5 structure: direct-global MFMA operands proved latency-bound in r6).
// Writes unnormalized O + (m,l) partials (fp32) for the combine pass.
// ---------------------------------------------------------------------------
__global__ __launch_bounds__(256, 4) void attn_kernel(const bf16* __restrict__ Qt,
                                                      const bf16* __restrict__ Kt,
                                                      const bf16* __restrict__ Vb,
                                                      float* __restrict__ Opart,
                                                      float* __restrict__ MLpart) {
    __shared__ __align__(16) bf16 Ktile[128][40];   // [k][d]   80B rows
    __shared__ __align__(16) bf16 Vtile[32][136];   // [d][k]   272B rows
    __shared__ __align__(16) bf16 Ptile[64][136];   // [q][k]   wave-private rows
    const int tid  = threadIdx.x;
    const int lane = tid & 63;
    const int wv   = tid >> 6;
    const int l15  = lane & 15, l4 = lane >> 4;
    const int bh    = blockIdx.y;
    const int split = blockIdx.z;
    const int q0 = blockIdx.x * 64;
    const int q  = q0 + wv * 16 + l15;

    const bf16* Kbh = Kt + (size_t)bh * NPIX * 32 + (size_t)split * KHALF * 32;
    const bf16* Vbh = Vb + (size_t)bh * 32 * NPIX + split * KHALF;

    // Q fragment: B[k=d][col=q], lane holds d = l4*8..+7 for its q column
    bf16x8 qf = *(const bf16x8*)&Qt[((size_t)bh * NPIX + q) * 32 + l4 * 8];

    // staging decomposition (same lanes load & store: global->reg->LDS)
    const int krow = tid >> 1, kcol = (tid & 1) * 16;
    const int vd   = tid >> 3, vc   = (tid & 7) * 16;
    const bf16* ksrc = Kbh + (size_t)krow * 32 + kcol;
    const bf16* vsrc = Vbh + (size_t)vd * NPIX + vc;

    bf16x8 ka, kb, va, vb_;
    ka  = *(const bf16x8*)(ksrc);
    kb  = *(const bf16x8*)(ksrc + 8);
    va  = *(const bf16x8*)(vsrc);
    vb_ = *(const bf16x8*)(vsrc + 8);
    *(bf16x8*)&Ktile[krow][kcol]     = ka;
    *(bf16x8*)&Ktile[krow][kcol + 8] = kb;
    *(bf16x8*)&Vtile[vd][vc]         = va;
    *(bf16x8*)&Vtile[vd][vc + 8]     = vb_;
    __syncthreads();

    f32x4 O0 = {}, O1 = {};
    float m_run = -INFINITY, l_run = 0.f;
    const int qrow = wv * 16 + l15;

    for (int kt = 0; kt < NITER; ++kt) {
        if (kt + 1 < NITER) {   // issue next-tile loads early (hidden under compute)
            const bf16* ks = ksrc + (size_t)(kt + 1) * TK * 32;
            const bf16* vs = vsrc + (kt + 1) * TK;
            ka  = *(const bf16x8*)(ks);
            kb  = *(const bf16x8*)(ks + 8);
            va  = *(const bf16x8*)(vs);
            vb_ = *(const bf16x8*)(vs + 8);
        }

        // S = K^T Q (K pre-scaled by scale*log2e). s[rt] = k-rows rt*16..+15
        f32x4 s[8];
        for (int rt = 0; rt < 8; ++rt) {
            bf16x8 a = *(const bf16x8*)&Ktile[rt * 16 + l15][l4 * 8];
            f32x4 z = {};
            s[rt] = __builtin_amdgcn_mfma_f32_16x16x32_bf16(a, qf, z, 0, 0, 0);
        }

        // online softmax over key dim (column q = lanes {l, l^16, l^32, l^48})
        float tmax = -INFINITY;
        for (int rt = 0; rt < 8; ++rt)
            for (int r = 0; r < 4; ++r) tmax = fmaxf(tmax, s[rt][r]);
        tmax = fmaxf(tmax, __shfl_xor(tmax, 16));
        tmax = fmaxf(tmax, __shfl_xor(tmax, 32));
        const float m_new = fmaxf(m_run, tmax);
        const float f = __builtin_amdgcn_exp2f(m_run - m_new);
        float psum = 0.f;
        for (int rt = 0; rt < 8; ++rt) {
            bf16x4 pk;
            for (int r = 0; r < 4; ++r) {
                float p = __builtin_amdgcn_exp2f(s[rt][r] - m_new);
                psum += p;
                pk[r] = (bf16)p;
            }
            *(bf16x4*)&Ptile[qrow][rt * 16 + l4 * 4] = pk;
        }
        psum += __shfl_xor(psum, 16);
        psum += __shfl_xor(psum, 32);
        l_run = l_run * f + psum;
        m_run = m_new;
        for (int i = 0; i < 4; ++i) { O0[i] *= f; O1[i] *= f; }

        // O += V * P  (A = V rows d, B = P cols q); 4 k-chunks of 32
        for (int ks = 0; ks < 4; ++ks) {
            bf16x8 pb = *(const bf16x8*)&Ptile[qrow][ks * 32 + l4 * 8];
            bf16x8 v0 = *(const bf16x8*)&Vtile[l15][ks * 32 + l4 * 8];
            bf16x8 v1 = *(const bf16x8*)&Vtile[16 + l15][ks * 32 + l4 * 8];
            O0 = __builtin_amdgcn_mfma_f32_16x16x32_bf16(v0, pb, O0, 0, 0, 0);
            O1 = __builtin_amdgcn_mfma_f32_16x16x32_bf16(v1, pb, O1, 0, 0, 0);
        }
        __syncthreads();               // all waves done reading tile kt
        if (kt + 1 < NITER) {          // commit prefetched tile kt+1
            *(bf16x8*)&Ktile[krow][kcol]     = ka;
            *(bf16x8*)&Ktile[krow][kcol + 8] = kb;
            *(bf16x8*)&Vtile[vd][vc]         = va;
            *(bf16x8*)&Vtile[vd][vc + 8]     = vb_;
        }
        __syncthreads();               // tile kt+1 visible
    }

    // store unnormalized partials
    f32x4* Op4 = (f32x4*)(Opart + ((size_t)(split * 16 + bh) * NPIX + q) * 32);
    Op4[l4]     = O0;   // d = l4*4 + r
    Op4[4 + l4] = O1;   // d = 16 + l4*4 + r
    if (l4 == 0) {
        f32x2 ml; ml[0] = m_run; ml[1] = l_run;
        *(f32x2*)&MLpart[((size_t)(split * 16 + bh) * NPIX + q) * 2] = ml;
    }
}

// ---------------------------------------------------------------------------
// Kernel 2b: fused epilogue — combine K-split partials + lepe (dw 3x3 + bias)
// Writes aout bf16 [c][n].  Grid (36, 16), 256 threads.
// ---------------------------------------------------------------------------
__global__ __launch_bounds__(256) void epilogue_kernel(const float* __restrict__ Opart,
                                                       const float* __restrict__ MLpart,
                                                       const bf16* __restrict__ Vb,
                                                       const float* __restrict__ wl,
                                                       const float* __restrict__ bl,
                                                       bf16* __restrict__ aout) {
    const int tid = threadIdx.x;
    const int bh  = blockIdx.y;
    const int q0  = blockIdx.x * 64;
    const int d   = tid >> 3;              // 0..31
    const int n8  = (tid & 7) * 8;         // 8 q per thread
    const int c   = bh * 32 + d;           // row in aout / Vb  (= b*256 + ch)
    const int ch  = c & 255;               // weight channel
    const float bias = bl[ch];
    float wgt[9];
    for (int i = 0; i < 9; ++i) wgt[i] = wl[ch * 9 + i];
    const bf16* vrow = Vb + (size_t)c * NPIX;

    for (int j = 0; j < 8; ++j) {
        const int q = q0 + n8 + j;
        // combine the two split partials
        f32x2 ml0 = *(const f32x2*)&MLpart[((size_t)bh * NPIX + q) * 2];
        f32x2 ml1 = *(const f32x2*)&MLpart[((size_t)(16 + bh) * NPIX + q) * 2];
        const float m  = fmaxf(ml0[0], ml1[0]);
        const float w0 = __builtin_amdgcn_exp2f(ml0[0] - m);
        const float w1 = __builtin_amdgcn_exp2f(ml1[0] - m);
        const float inv = 1.f / (w0 * ml0[1] + w1 * ml1[1]);
        const float o0 = Opart[((size_t)bh * NPIX + q) * 32 + d];
        const float o1 = Opart[((size_t)(16 + bh) * NPIX + q) * 32 + d];
        float val = (w0 * o0 + w1 * o1) * inv;
        // lepe: depthwise 3x3 over the 48x48 image, channel c
        const int y = q / WIMG, xx = q % WIMG;
        float acc = bias;
        for (int dy = -1; dy <= 1; ++dy) {
            const int yy = y + dy;
            if (yy < 0 || yy >= WIMG) continue;
            for (int dx = -1; dx <= 1; ++dx) {
                const int xc = xx + dx;
                if (xc < 0 || xc >= WIMG) continue;
                acc += (float)vrow[yy * WIMG + xc] * wgt[(dy + 1) * 3 + dx + 1];
            }
        }
        aout[(size_t)c * NPIX + q] = (bf16)(val + acc);
    }
}

// ---------------------------------------------------------------------------
// Kernel 4: out = w_proj @ attn_out + b_proj  (fp32 output)
// ---------------------------------------------------------------------------
__global__ __launch_bounds__(256) void proj_gemm(const bf16* __restrict__ ain,
                                                 const float* __restrict__ w,
                                                 const float* __restrict__ bp,
                                                 float* __restrict__ out) {
    __shared__ __align__(16) bf16 aT[64][40];
    const int tid  = threadIdx.x;
    const int lane = tid & 63;
    const int wv   = tid >> 6;
    const int wn   = wv & 1, wo = wv >> 1;
    const int l15  = lane & 15, l4 = lane >> 4;
    const int g0 = blockIdx.x * 64;
    const int b  = g0 / NPIX;
    const int n0 = g0 % NPIX;
    const int o0 = blockIdx.y * 64;
    const bf16* ab = ain + (size_t)b * CCH * NPIX;

    f32x4 acc[2][2] = {};
    for (int kc = 0; kc < 8; ++kc) {
        const int c0 = kc * 32;
        for (int r = 0; r < 8; ++r) {
            int idx = r * 256 + tid;
            int ci = idx >> 6, n = idx & 63;
            aT[n][ci] = ab[(size_t)(c0 + ci) * NPIX + n0 + n];
        }
        __syncthreads();
        bf16x8 afr[2], bfr[2];
        for (int at = 0; at < 2; ++at) {
            const float* wp = w + (size_t)(o0 + wo * 32 + at * 16 + l15) * CCH + c0 + l4 * 8;
            f32x4 w0 = *(const f32x4*)wp;
            f32x4 w1 = *(const f32x4*)(wp + 4);
            bf16x8 a;
            for (int i = 0; i < 4; ++i) { a[i] = (bf16)w0[i]; a[i + 4] = (bf16)w1[i]; }
            afr[at] = a;
        }
        for (int bt = 0; bt < 2; ++bt)
            bfr[bt] = *(const bf16x8*)&aT[wn * 32 + bt * 16 + l15][l4 * 8];
        for (int at = 0; at < 2; ++at)
            for (int bt = 0; bt < 2; ++bt)
                acc[at][bt] = __builtin_amdgcn_mfma_f32_16x16x32_bf16(afr[at], bfr[bt],
                                                                     acc[at][bt], 0, 0, 0);
        __syncthreads();
    }
    for (int at = 0; at < 2; ++at)
        for (int bt = 0; bt < 2; ++bt) {
            const int n = n0 + wn * 32 + bt * 16 + l15;
            for (int r = 0; r < 4; ++r) {
                const int o = o0 + wo * 32 + at * 16 + l4 * 4 + r;
                out[(size_t)(b * 256 + o) * NPIX + n] = acc[at][bt][r] + bp[o];
            }
        }
}

// ---------------------------------------------------------------------------
extern "C" void kernel_launch(void* const* d_in, const int* in_sizes, int n_in,
                              void* d_out, int out_size, void* d_ws, size_t ws_size,
                              hipStream_t stream) {
    const float* x      = (const float*)d_in[0];
    const float* w_qkv  = (const float*)d_in[1];
    const float* w_lepe = (const float*)d_in[2];
    const float* b_lepe = (const float*)d_in[3];
    const float* w_proj = (const float*)d_in[4];
    const float* b_proj = (const float*)d_in[5];
    float* out = (float*)d_out;

    // ws layout: Qt|Kt|V|aout (bf16, 4 x 1179648 elems = 9.44MB),
    // then Opart fp32 (2*16*2304*32 = 9.44MB), MLpart fp32 (0.59MB)
    bf16* Qt   = (bf16*)d_ws;
    bf16* Kt   = Qt + 1179648;
    bf16* Vb   = Kt + 1179648;
    bf16* aout = Vb + 1179648;
    float* Opart  = (float*)((char*)d_ws + 9437184);
    float* MLpart = Opart + 2359296;

    qkv_gemm      <<<dim3(72, 12),    256, 0, stream>>>(x, w_qkv, Qt, Kt, Vb);
    attn_kernel   <<<dim3(36, 16, 2), 256, 0, stream>>>(Qt, Kt, Vb, Opart, MLpart);
    epilogue_kernel<<<dim3(36, 16),   256, 0, stream>>>(Opart, MLpart, Vb, w_lepe, b_lepe, aout);
    proj_gemm     <<<dim3(72, 4),     256, 0, stream>>>(aout, w_proj, b_proj, out);
}

// Round 12
// 164.715 us; speedup vs baseline: 1.2156x; 1.0297x over previous
//
#include <hip/hip_runtime.h>
#include <hip/hip_bf16.h>

typedef __bf16 bf16;
typedef __bf16 bf16x8 __attribute__((ext_vector_type(8)));
typedef __bf16 bf16x4 __attribute__((ext_vector_type(4)));
typedef float  f32x4  __attribute__((ext_vector_type(4)));
typedef float  f32x2  __attribute__((ext_vector_type(2)));

#define NB    2
#define CCH   256
#define NPIX  2304
#define WIMG  48
// scale * log2(e) = (1/sqrt(32)) * 1.4426950408889634  (folded into Kt)
#define SLOG2E 0.25503487f
#define NSPLIT 4
#define KSEG   576
#define TK     64
#define NITER  9

// ---------------------------------------------------------------------------
// Kernel 1: qkv = w_qkv @ x   (M=768, K=256, cols = B*2304)
// Qt/Kt as [bh][n][32] bf16 (token-major; Kt pre-scaled by scale*log2e),
// V as [bh][32][n] bf16.
// ---------------------------------------------------------------------------
__global__ __launch_bounds__(256) void qkv_gemm(const float* __restrict__ x,
                                                const float* __restrict__ w,
                                                bf16* __restrict__ Qt,
                                                bf16* __restrict__ Kt,
                                                bf16* __restrict__ Vb) {
    __shared__ __align__(16) bf16 xT[64][40];   // [n][c] transposed tile, padded
    const int tid  = threadIdx.x;
    const int lane = tid & 63;
    const int wv   = tid >> 6;
    const int wn   = wv & 1, wo = wv >> 1;
    const int l15  = lane & 15, l4 = lane >> 4;
    const int g0 = blockIdx.x * 64;
    const int b  = g0 / NPIX;
    const int n0 = g0 % NPIX;
    const int o0 = blockIdx.y * 64;
    const float* xb = x + (size_t)b * CCH * NPIX;

    f32x4 acc[2][2] = {};

    for (int kc = 0; kc < 8; ++kc) {
        const int c0 = kc * 32;
        for (int r = 0; r < 8; ++r) {
            int idx = r * 256 + tid;
            int c = idx >> 6, n = idx & 63;
            xT[n][c] = (bf16)xb[(size_t)(c0 + c) * NPIX + n0 + n];
        }
        __syncthreads();
        bf16x8 afr[2], bfr[2];
        for (int at = 0; at < 2; ++at) {
            const float* wp = w + (size_t)(o0 + wo * 32 + at * 16 + l15) * CCH + c0 + l4 * 8;
            f32x4 w0 = *(const f32x4*)wp;
            f32x4 w1 = *(const f32x4*)(wp + 4);
            bf16x8 a;
            for (int i = 0; i < 4; ++i) { a[i] = (bf16)w0[i]; a[i + 4] = (bf16)w1[i]; }
            afr[at] = a;
        }
        for (int bt = 0; bt < 2; ++bt)
            bfr[bt] = *(const bf16x8*)&xT[wn * 32 + bt * 16 + l15][l4 * 8];
        for (int at = 0; at < 2; ++at)
            for (int bt = 0; bt < 2; ++bt)
                acc[at][bt] = __builtin_amdgcn_mfma_f32_16x16x32_bf16(afr[at], bfr[bt],
                                                                     acc[at][bt], 0, 0, 0);
        __syncthreads();
    }

    for (int at = 0; at < 2; ++at) {
        const int otile = o0 + wo * 32 + at * 16;
        const int h    = otile / 96;
        const int role = (otile % 96) / 32;            // 0=q 1=k 2=v
        const int ddb  = (otile % 32) + l4 * 4;
        const int bh   = b * 8 + h;
        for (int bt = 0; bt < 2; ++bt) {
            const int n = n0 + wn * 32 + bt * 16 + l15;
            if (role == 2) {
                for (int r = 0; r < 4; ++r)
                    Vb[(size_t)(bh * 32 + ddb + r) * NPIX + n] = (bf16)acc[at][bt][r];
            } else if (role == 1) {
                bf16x4 pk;
                for (int r = 0; r < 4; ++r) pk[r] = (bf16)(acc[at][bt][r] * SLOG2E);
                *(bf16x4*)&Kt[((size_t)bh * NPIX + n) * 32 + ddb] = pk;
            } else {
                bf16x4 pk;
                for (int r = 0; r < 4; ++r) pk[r] = (bf16)acc[at][bt][r];
                *(bf16x4*)&Qt[((size_t)bh * NPIX + n) * 32 + ddb] = pk;
            }
        }
    }
}

// ---------------------------------------------------------------------------
// Kernel 2: flash attention, K-split x4. Grid (36, 16, 4) = 2304 blocks
// (9/CU; LDS 18.9KB -> 8 blocks/CU, full 32-wave occupancy).
// Tk=64, 9 iters/block, LDS-staged K/V with register-prefetch double buffer.
// Writes unnormalized O + (m,l) partials (fp32) for the combine pass.
// ---------------------------------------------------------------------------
__global__ __launch_bounds__(256, 4) void attn_kernel(const bf16* __restrict__ Qt,
                                                      const bf16* __restrict__ Kt,
                                                      const bf16* __restrict__ Vb,
                                                      float* __restrict__ Opart,
                                                      float* __restrict__ MLpart) {
    __shared__ __align__(16) bf16 Ktile[64][40];    // [k][d]  80B rows
    __shared__ __align__(16) bf16 Vtile[32][72];    // [d][k]  144B rows
    __shared__ __align__(16) bf16 Ptile[64][72];    // [q][k]  wave-private rows
    const int tid  = threadIdx.x;
    const int lane = tid & 63;
    const int wv   = tid >> 6;
    const int l15  = lane & 15, l4 = lane >> 4;
    const int bh    = blockIdx.y;
    const int split = blockIdx.z;
    const int q0 = blockIdx.x * 64;
    const int q  = q0 + wv * 16 + l15;

    const bf16* Kbh = Kt + (size_t)bh * NPIX * 32 + (size_t)split * KSEG * 32;
    const bf16* Vbh = Vb + (size_t)bh * 32 * NPIX + split * KSEG;

    // Q fragment: B[k=d][col=q], lane holds d = l4*8..+7 for its q column
    bf16x8 qf = *(const bf16x8*)&Qt[((size_t)bh * NPIX + q) * 32 + l4 * 8];

    // staging decomposition (one bf16x8 per thread for K and V)
    const int krow = tid >> 2, kcol = (tid & 3) * 8;
    const int vd   = tid >> 3, vc   = (tid & 7) * 8;
    const bf16* ksrc = Kbh + (size_t)krow * 32 + kcol;
    const bf16* vsrc = Vbh + (size_t)vd * NPIX + vc;

    bf16x8 ka, va;
    ka = *(const bf16x8*)(ksrc);
    va = *(const bf16x8*)(vsrc);
    *(bf16x8*)&Ktile[krow][kcol] = ka;
    *(bf16x8*)&Vtile[vd][vc]     = va;
    __syncthreads();

    f32x4 O0 = {}, O1 = {};
    float m_run = -INFINITY, l_run = 0.f;
    const int qrow = wv * 16 + l15;

    for (int kt = 0; kt < NITER; ++kt) {
        if (kt + 1 < NITER) {   // issue next-tile loads early (hidden under compute)
            ka = *(const bf16x8*)(ksrc + (size_t)(kt + 1) * TK * 32);
            va = *(const bf16x8*)(vsrc + (kt + 1) * TK);
        }

        // S = K^T Q (K pre-scaled by scale*log2e). s[rt] = k-rows rt*16..+15
        f32x4 s[4];
        for (int rt = 0; rt < 4; ++rt) {
            bf16x8 a = *(const bf16x8*)&Ktile[rt * 16 + l15][l4 * 8];
            f32x4 z = {};
            s[rt] = __builtin_amdgcn_mfma_f32_16x16x32_bf16(a, qf, z, 0, 0, 0);
        }

        // online softmax over key dim (column q = lanes {l, l^16, l^32, l^48})
        float tmax = -INFINITY;
        for (int rt = 0; rt < 4; ++rt)
            for (int r = 0; r < 4; ++r) tmax = fmaxf(tmax, s[rt][r]);
        tmax = fmaxf(tmax, __shfl_xor(tmax, 16));
        tmax = fmaxf(tmax, __shfl_xor(tmax, 32));
        const float m_new = fmaxf(m_run, tmax);
        const float f = __builtin_amdgcn_exp2f(m_run - m_new);
        float psum = 0.f;
        for (int rt = 0; rt < 4; ++rt) {
            bf16x4 pk;
            for (int r = 0; r < 4; ++r) {
                float p = __builtin_amdgcn_exp2f(s[rt][r] - m_new);
                psum += p;
                pk[r] = (bf16)p;
            }
            *(bf16x4*)&Ptile[qrow][rt * 16 + l4 * 4] = pk;
        }
        psum += __shfl_xor(psum, 16);
        psum += __shfl_xor(psum, 32);
        l_run = l_run * f + psum;
        m_run = m_new;
        for (int i = 0; i < 4; ++i) { O0[i] *= f; O1[i] *= f; }

        // O += V * P  (A = V rows d, B = P cols q); 2 k-chunks of 32
        for (int ks = 0; ks < 2; ++ks) {
            bf16x8 pb = *(const bf16x8*)&Ptile[qrow][ks * 32 + l4 * 8];
            bf16x8 v0 = *(const bf16x8*)&Vtile[l15][ks * 32 + l4 * 8];
            bf16x8 v1 = *(const bf16x8*)&Vtile[16 + l15][ks * 32 + l4 * 8];
            O0 = __builtin_amdgcn_mfma_f32_16x16x32_bf16(v0, pb, O0, 0, 0, 0);
            O1 = __builtin_amdgcn_mfma_f32_16x16x32_bf16(v1, pb, O1, 0, 0, 0);
        }
        __syncthreads();               // all waves done reading tile kt
        if (kt + 1 < NITER) {          // commit prefetched tile kt+1
            *(bf16x8*)&Ktile[krow][kcol] = ka;
            *(bf16x8*)&Vtile[vd][vc]     = va;
        }
        __syncthreads();               // tile kt+1 visible
    }

    // store unnormalized partials
    f32x4* Op4 = (f32x4*)(Opart + ((size_t)(split * 16 + bh) * NPIX + q) * 32);
    Op4[l4]     = O0;   // d = l4*4 + r
    Op4[4 + l4] = O1;   // d = 16 + l4*4 + r
    if (l4 == 0) {
        f32x2 ml; ml[0] = m_run; ml[1] = l_run;
        *(f32x2*)&MLpart[((size_t)(split * 16 + bh) * NPIX + q) * 2] = ml;
    }
}

// ---------------------------------------------------------------------------
// Kernel 2b: fused epilogue — combine 4 K-split partials + lepe (dw 3x3+bias).
// 3 phases: (0) per-q combine weights, (1) coalesced Opart reduce -> LDS,
// (2) lepe + row-contiguous aout write.  Grid (36, 16), 256 threads.
// ---------------------------------------------------------------------------
__global__ __launch_bounds__(256) void epilogue_kernel(const float* __restrict__ Opart,
                                                       const float* __restrict__ MLpart,
                                                       const bf16* __restrict__ Vb,
                                                       const float* __restrict__ wl,
                                                       const float* __restrict__ bl,
                                                       bf16* __restrict__ aout) {
    __shared__ float wnorm[NSPLIT][72];   // normalized weight w_s/denom per q
    __shared__ float vals[32][69];        // combined attention values [d][q]
    const int tid = threadIdx.x;
    const int bh  = blockIdx.y;
    const int q0  = blockIdx.x * 64;

    // phase 0: per-q combine weights (threads 0..63, coalesced MLpart reads)
    if (tid < 64) {
        const int q = q0 + tid;
        float mv[NSPLIT], lv[NSPLIT], m = -INFINITY;
        for (int s = 0; s < NSPLIT; ++s) {
            f32x2 ml = *(const f32x2*)&MLpart[((size_t)(s * 16 + bh) * NPIX + q) * 2];
            mv[s] = ml[0]; lv[s] = ml[1];
            m = fmaxf(m, ml[0]);
        }
        float wsv[NSPLIT], denom = 0.f;
        for (int s = 0; s < NSPLIT; ++s) {
            wsv[s] = __builtin_amdgcn_exp2f(mv[s] - m);
            denom += wsv[s] * lv[s];
        }
        const float inv = 1.f / denom;
        for (int s = 0; s < NSPLIT; ++s) wnorm[s][tid] = wsv[s] * inv;
    }
    __syncthreads();

    // phase 1: weighted Opart reduce, d fast-varying (coalesced 128B/32 lanes)
    {
        const int d  = tid & 31;
        const int qg = tid >> 5;          // 0..7, 8 q each
        for (int j = 0; j < 8; ++j) {
            const int qq = qg * 8 + j;
            const int q  = q0 + qq;
            float v = 0.f;
            for (int s = 0; s < NSPLIT; ++s)
                v += wnorm[s][qq] * Opart[((size_t)(s * 16 + bh) * NPIX + q) * 32 + d];
            vals[d][qq] = v;
        }
    }
    __syncthreads();

    // phase 2: lepe + write (8 contiguous q per thread, row-contiguous stores)
    const int d2 = tid >> 3;              // 0..31
    const int n8 = (tid & 7) * 8;
    const int c  = bh * 32 + d2;          // row in aout / Vb (= b*256 + ch)
    const int ch = c & 255;
    const float bias = bl[ch];
    float wgt[9];
    for (int i = 0; i < 9; ++i) wgt[i] = wl[ch * 9 + i];
    const bf16* vrow = Vb + (size_t)c * NPIX;

    for (int j = 0; j < 8; ++j) {
        const int q = q0 + n8 + j;
        float val = vals[d2][n8 + j];
        const int y = q / WIMG, xx = q % WIMG;
        float acc = bias;
        for (int dy = -1; dy <= 1; ++dy) {
            const int yy = y + dy;
            if (yy < 0 || yy >= WIMG) continue;
            for (int dx = -1; dx <= 1; ++dx) {
                const int xc = xx + dx;
                if (xc < 0 || xc >= WIMG) continue;
                acc += (float)vrow[yy * WIMG + xc] * wgt[(dy + 1) * 3 + dx + 1];
            }
        }
        aout[(size_t)c * NPIX + q] = (bf16)(val + acc);
    }
}

// ---------------------------------------------------------------------------
// Kernel 4: out = w_proj @ attn_out + b_proj  (fp32 output)
// ---------------------------------------------------------------------------
__global__ __launch_bounds__(256) void proj_gemm(const bf16* __restrict__ ain,
                                                 const float* __restrict__ w,
                                                 const float* __restrict__ bp,
                                                 float* __restrict__ out) {
    __shared__ __align__(16) bf16 aT[64][40];
    const int tid  = threadIdx.x;
    const int lane = tid & 63;
    const int wv   = tid >> 6;
    const int wn   = wv & 1, wo = wv >> 1;
    const int l15  = lane & 15, l4 = lane >> 4;
    const int g0 = blockIdx.x * 64;
    const int b  = g0 / NPIX;
    const int n0 = g0 % NPIX;
    const int o0 = blockIdx.y * 64;
    const bf16* ab = ain + (size_t)b * CCH * NPIX;

    f32x4 acc[2][2] = {};
    for (int kc = 0; kc < 8; ++kc) {
        const int c0 = kc * 32;
        for (int r = 0; r < 8; ++r) {
            int idx = r * 256 + tid;
            int ci = idx >> 6, n = idx & 63;
            aT[n][ci] = ab[(size_t)(c0 + ci) * NPIX + n0 + n];
        }
        __syncthreads();
        bf16x8 afr[2], bfr[2];
        for (int at = 0; at < 2; ++at) {
            const float* wp = w + (size_t)(o0 + wo * 32 + at * 16 + l15) * CCH + c0 + l4 * 8;
            f32x4 w0 = *(const f32x4*)wp;
            f32x4 w1 = *(const f32x4*)(wp + 4);
            bf16x8 a;
            for (int i = 0; i < 4; ++i) { a[i] = (bf16)w0[i]; a[i + 4] = (bf16)w1[i]; }
            afr[at] = a;
        }
        for (int bt = 0; bt < 2; ++bt)
            bfr[bt] = *(const bf16x8*)&aT[wn * 32 + bt * 16 + l15][l4 * 8];
        for (int at = 0; at < 2; ++at)
            for (int bt = 0; bt < 2; ++bt)
                acc[at][bt] = __builtin_amdgcn_mfma_f32_16x16x32_bf16(afr[at], bfr[bt],
                                                                     acc[at][bt], 0, 0, 0);
        __syncthreads();
    }
    for (int at = 0; at < 2; ++at)
        for (int bt = 0; bt < 2; ++bt) {
            const int n = n0 + wn * 32 + bt * 16 + l15;
            for (int r = 0; r < 4; ++r) {
                const int o = o0 + wo * 32 + at * 16 + l4 * 4 + r;
                out[(size_t)(b * 256 + o) * NPIX + n] = acc[at][bt][r] + bp[o];
            }
        }
}

// ---------------------------------------------------------------------------
extern "C" void kernel_launch(void* const* d_in, const int* in_sizes, int n_in,
                              void* d_out, int out_size, void* d_ws, size_t ws_size,
                              hipStream_t stream) {
    const float* x      = (const float*)d_in[0];
    const float* w_qkv  = (const float*)d_in[1];
    const float* w_lepe = (const float*)d_in[2];
    const float* b_lepe = (const float*)d_in[3];
    const float* w_proj = (const float*)d_in[4];
    const float* b_proj = (const float*)d_in[5];
    float* out = (float*)d_out;

    // ws layout: Qt|Kt|V|aout (bf16, 4 x 1179648 elems = 9.44MB),
    // then Opart fp32 (4*16*2304*32 = 18.9MB), MLpart fp32 (1.2MB)
    bf16* Qt   = (bf16*)d_ws;
    bf16* Kt   = Qt + 1179648;
    bf16* Vb   = Kt + 1179648;
    bf16* aout = Vb + 1179648;
    float* Opart  = (float*)((char*)d_ws + 9437184);
    float* MLpart = Opart + 4718592;

    qkv_gemm      <<<dim3(72, 12),    256, 0, stream>>>(x, w_qkv, Qt, Kt, Vb);
    attn_kernel   <<<dim3(36, 16, 4), 256, 0, stream>>>(Qt, Kt, Vb, Opart, MLpart);
    epilogue_kernel<<<dim3(36, 16),   256, 0, stream>>>(Opart, MLpart, Vb, w_lepe, b_lepe, aout);
    proj_gemm     <<<dim3(72, 4),     256, 0, stream>>>(aout, w_proj, b_proj, out);
}

// Round 14
// 145.193 us; speedup vs baseline: 1.3791x; 1.1345x over previous
//
#include <hip/hip_runtime.h>
#include <hip/hip_bf16.h>

typedef __bf16 bf16;
typedef __bf16 bf16x8 __attribute__((ext_vector_type(8)));
typedef __bf16 bf16x4 __attribute__((ext_vector_type(4)));
typedef __bf16 bf16x2 __attribute__((ext_vector_type(2)));
typedef unsigned short ushort8 __attribute__((ext_vector_type(8)));
typedef float  f32x4  __attribute__((ext_vector_type(4)));
typedef float  f32x2  __attribute__((ext_vector_type(2)));

#define NB    2
#define CCH   256
#define NPIX  2304
#define WIMG  48
// scale * log2(e) = (1/sqrt(32)) * 1.4426950408889634  (folded into Kt)
#define SLOG2E 0.25503487f
#define NSPLIT 4
#define KSEG   576
#define TK     64
#define NITER  9

// ---------------------------------------------------------------------------
// Kernel 1: qkv = w_qkv @ x   (M=768, K=256, cols = B*2304)
// v2: whole-K LDS staging (1 barrier), f32x4-pair transpose, vectorized.
// Qt/Kt as [bh][n][32] bf16 (Kt pre-scaled by scale*log2e), V as [bh][32][n].
// ---------------------------------------------------------------------------
__global__ __launch_bounds__(256) void qkv_gemm(const float* __restrict__ x,
                                                const float* __restrict__ w,
                                                bf16* __restrict__ Qt,
                                                bf16* __restrict__ Kt,
                                                bf16* __restrict__ Vb) {
    __shared__ __align__(16) bf16 xT[64][264];  // [n][c], rows 528B (16B-mult, read-friendly)
    const int tid  = threadIdx.x;
    const int lane = tid & 63;
    const int wv   = tid >> 6;
    const int wn   = wv & 1, wo = wv >> 1;
    const int l15  = lane & 15, l4 = lane >> 4;
    const int g0 = blockIdx.x * 64;
    const int b  = g0 / NPIX;
    const int n0 = g0 % NPIX;
    const int o0 = blockIdx.y * 64;
    const float* xb = x + (size_t)b * CCH * NPIX;

    // stage whole 64n x 256c tile: pairs of c-rows, 4 n per thread-unit
    {
        const int nq  = (tid & 15) * 4;
        const int cp0 = tid >> 4;            // 0..15
        for (int i = 0; i < 8; ++i) {
            const int c = (i * 16 + cp0) * 2;
            f32x4 a0 = *(const f32x4*)&xb[(size_t)c * NPIX + n0 + nq];
            f32x4 a1 = *(const f32x4*)&xb[(size_t)(c + 1) * NPIX + n0 + nq];
            for (int j = 0; j < 4; ++j) {
                bf16x2 p; p[0] = (bf16)a0[j]; p[1] = (bf16)a1[j];
                *(bf16x2*)&xT[nq + j][c] = p;
            }
        }
    }
    __syncthreads();

    f32x4 acc[2][2] = {};
    for (int kc = 0; kc < 8; ++kc) {
        bf16x8 afr[2], bfr[2];
        for (int at = 0; at < 2; ++at) {
            const float* wp = w + (size_t)(o0 + wo * 32 + at * 16 + l15) * CCH + kc * 32 + l4 * 8;
            f32x4 w0 = *(const f32x4*)wp;
            f32x4 w1 = *(const f32x4*)(wp + 4);
            bf16x8 a;
            for (int i = 0; i < 4; ++i) { a[i] = (bf16)w0[i]; a[i + 4] = (bf16)w1[i]; }
            afr[at] = a;
        }
        for (int bt = 0; bt < 2; ++bt)
            bfr[bt] = *(const bf16x8*)&xT[wn * 32 + bt * 16 + l15][kc * 32 + l4 * 8];
        for (int at = 0; at < 2; ++at)
            for (int bt = 0; bt < 2; ++bt)
                acc[at][bt] = __builtin_amdgcn_mfma_f32_16x16x32_bf16(afr[at], bfr[bt],
                                                                     acc[at][bt], 0, 0, 0);
    }

    for (int at = 0; at < 2; ++at) {
        const int otile = o0 + wo * 32 + at * 16;
        const int h    = otile / 96;
        const int role = (otile % 96) / 32;            // 0=q 1=k 2=v
        const int ddb  = (otile % 32) + l4 * 4;
        const int bh   = b * 8 + h;
        for (int bt = 0; bt < 2; ++bt) {
            const int n = n0 + wn * 32 + bt * 16 + l15;
            if (role == 2) {
                for (int r = 0; r < 4; ++r)
                    Vb[(size_t)(bh * 32 + ddb + r) * NPIX + n] = (bf16)acc[at][bt][r];
            } else if (role == 1) {
                bf16x4 pk;
                for (int r = 0; r < 4; ++r) pk[r] = (bf16)(acc[at][bt][r] * SLOG2E);
                *(bf16x4*)&Kt[((size_t)bh * NPIX + n) * 32 + ddb] = pk;
            } else {
                bf16x4 pk;
                for (int r = 0; r < 4; ++r) pk[r] = (bf16)acc[at][bt][r];
                *(bf16x4*)&Qt[((size_t)bh * NPIX + n) * 32 + ddb] = pk;
            }
        }
    }
}

// ---------------------------------------------------------------------------
// Kernel 2: flash attention, K-split x4. Grid (36, 16, 4) — unchanged (r12).
// ---------------------------------------------------------------------------
__global__ __launch_bounds__(256, 4) void attn_kernel(const bf16* __restrict__ Qt,
                                                      const bf16* __restrict__ Kt,
                                                      const bf16* __restrict__ Vb,
                                                      float* __restrict__ Opart,
                                                      float* __restrict__ MLpart) {
    __shared__ __align__(16) bf16 Ktile[64][40];    // [k][d]  80B rows
    __shared__ __align__(16) bf16 Vtile[32][72];    // [d][k]  144B rows
    __shared__ __align__(16) bf16 Ptile[64][72];    // [q][k]  wave-private rows
    const int tid  = threadIdx.x;
    const int lane = tid & 63;
    const int wv   = tid >> 6;
    const int l15  = lane & 15, l4 = lane >> 4;
    const int bh    = blockIdx.y;
    const int split = blockIdx.z;
    const int q0 = blockIdx.x * 64;
    const int q  = q0 + wv * 16 + l15;

    const bf16* Kbh = Kt + (size_t)bh * NPIX * 32 + (size_t)split * KSEG * 32;
    const bf16* Vbh = Vb + (size_t)bh * 32 * NPIX + split * KSEG;

    bf16x8 qf = *(const bf16x8*)&Qt[((size_t)bh * NPIX + q) * 32 + l4 * 8];

    const int krow = tid >> 2, kcol = (tid & 3) * 8;
    const int vd   = tid >> 3, vc   = (tid & 7) * 8;
    const bf16* ksrc = Kbh + (size_t)krow * 32 + kcol;
    const bf16* vsrc = Vbh + (size_t)vd * NPIX + vc;

    bf16x8 ka, va;
    ka = *(const bf16x8*)(ksrc);
    va = *(const bf16x8*)(vsrc);
    *(bf16x8*)&Ktile[krow][kcol] = ka;
    *(bf16x8*)&Vtile[vd][vc]     = va;
    __syncthreads();

    f32x4 O0 = {}, O1 = {};
    float m_run = -INFINITY, l_run = 0.f;
    const int qrow = wv * 16 + l15;

    for (int kt = 0; kt < NITER; ++kt) {
        if (kt + 1 < NITER) {
            ka = *(const bf16x8*)(ksrc + (size_t)(kt + 1) * TK * 32);
            va = *(const bf16x8*)(vsrc + (kt + 1) * TK);
        }

        f32x4 s[4];
        for (int rt = 0; rt < 4; ++rt) {
            bf16x8 a = *(const bf16x8*)&Ktile[rt * 16 + l15][l4 * 8];
            f32x4 z = {};
            s[rt] = __builtin_amdgcn_mfma_f32_16x16x32_bf16(a, qf, z, 0, 0, 0);
        }

        float tmax = -INFINITY;
        for (int rt = 0; rt < 4; ++rt)
            for (int r = 0; r < 4; ++r) tmax = fmaxf(tmax, s[rt][r]);
        tmax = fmaxf(tmax, __shfl_xor(tmax, 16));
        tmax = fmaxf(tmax, __shfl_xor(tmax, 32));
        const float m_new = fmaxf(m_run, tmax);
        const float f = __builtin_amdgcn_exp2f(m_run - m_new);
        float psum = 0.f;
        for (int rt = 0; rt < 4; ++rt) {
            bf16x4 pk;
            for (int r = 0; r < 4; ++r) {
                float p = __builtin_amdgcn_exp2f(s[rt][r] - m_new);
                psum += p;
                pk[r] = (bf16)p;
            }
            *(bf16x4*)&Ptile[qrow][rt * 16 + l4 * 4] = pk;
        }
        psum += __shfl_xor(psum, 16);
        psum += __shfl_xor(psum, 32);
        l_run = l_run * f + psum;
        m_run = m_new;
        for (int i = 0; i < 4; ++i) { O0[i] *= f; O1[i] *= f; }

        for (int ks = 0; ks < 2; ++ks) {
            bf16x8 pb = *(const bf16x8*)&Ptile[qrow][ks * 32 + l4 * 8];
            bf16x8 v0 = *(const bf16x8*)&Vtile[l15][ks * 32 + l4 * 8];
            bf16x8 v1 = *(const bf16x8*)&Vtile[16 + l15][ks * 32 + l4 * 8];
            O0 = __builtin_amdgcn_mfma_f32_16x16x32_bf16(v0, pb, O0, 0, 0, 0);
            O1 = __builtin_amdgcn_mfma_f32_16x16x32_bf16(v1, pb, O1, 0, 0, 0);
        }
        __syncthreads();
        if (kt + 1 < NITER) {
            *(bf16x8*)&Ktile[krow][kcol] = ka;
            *(bf16x8*)&Vtile[vd][vc]     = va;
        }
        __syncthreads();
    }

    f32x4* Op4 = (f32x4*)(Opart + ((size_t)(split * 16 + bh) * NPIX + q) * 32);
    Op4[l4]     = O0;
    Op4[4 + l4] = O1;
    if (l4 == 0) {
        f32x2 ml; ml[0] = m_run; ml[1] = l_run;
        *(f32x2*)&MLpart[((size_t)(split * 16 + bh) * NPIX + q) * 2] = ml;
    }
}

// ---------------------------------------------------------------------------
// Kernel 2b: fused epilogue — combine 4 K-split partials + lepe — unchanged.
// ---------------------------------------------------------------------------
__global__ __launch_bounds__(256) void epilogue_kernel(const float* __restrict__ Opart,
                                                       const float* __restrict__ MLpart,
                                                       const bf16* __restrict__ Vb,
                                                       const float* __restrict__ wl,
                                                       const float* __restrict__ bl,
                                                       bf16* __restrict__ aout) {
    __shared__ float wnorm[NSPLIT][72];
    __shared__ float vals[32][69];
    const int tid = threadIdx.x;
    const int bh  = blockIdx.y;
    const int q0  = blockIdx.x * 64;

    if (tid < 64) {
        const int q = q0 + tid;
        float mv[NSPLIT], lv[NSPLIT], m = -INFINITY;
        for (int s = 0; s < NSPLIT; ++s) {
            f32x2 ml = *(const f32x2*)&MLpart[((size_t)(s * 16 + bh) * NPIX + q) * 2];
            mv[s] = ml[0]; lv[s] = ml[1];
            m = fmaxf(m, ml[0]);
        }
        float wsv[NSPLIT], denom = 0.f;
        for (int s = 0; s < NSPLIT; ++s) {
            wsv[s] = __builtin_amdgcn_exp2f(mv[s] - m);
            denom += wsv[s] * lv[s];
        }
        const float inv = 1.f / denom;
        for (int s = 0; s < NSPLIT; ++s) wnorm[s][tid] = wsv[s] * inv;
    }
    __syncthreads();

    {
        const int d  = tid & 31;
        const int qg = tid >> 5;
        for (int j = 0; j < 8; ++j) {
            const int qq = qg * 8 + j;
            const int q  = q0 + qq;
            float v = 0.f;
            for (int s = 0; s < NSPLIT; ++s)
                v += wnorm[s][qq] * Opart[((size_t)(s * 16 + bh) * NPIX + q) * 32 + d];
            vals[d][qq] = v;
        }
    }
    __syncthreads();

    const int d2 = tid >> 3;
    const int n8 = (tid & 7) * 8;
    const int c  = bh * 32 + d2;
    const int ch = c & 255;
    const float bias = bl[ch];
    float wgt[9];
    for (int i = 0; i < 9; ++i) wgt[i] = wl[ch * 9 + i];
    const bf16* vrow = Vb + (size_t)c * NPIX;

    for (int j = 0; j < 8; ++j) {
        const int q = q0 + n8 + j;
        float val = vals[d2][n8 + j];
        const int y = q / WIMG, xx = q % WIMG;
        float acc = bias;
        for (int dy = -1; dy <= 1; ++dy) {
            const int yy = y + dy;
            if (yy < 0 || yy >= WIMG) continue;
            for (int dx = -1; dx <= 1; ++dx) {
                const int xc = xx + dx;
                if (xc < 0 || xc >= WIMG) continue;
                acc += (float)vrow[yy * WIMG + xc] * wgt[(dy + 1) * 3 + dx + 1];
            }
        }
        aout[(size_t)c * NPIX + q] = (bf16)(val + acc);
    }
}

// ---------------------------------------------------------------------------
// Kernel 4: out = w_proj @ attn_out + b_proj  (fp32 output)
// v2: whole-K LDS staging (1 barrier), bf16x8-pair interleave transpose.
// ---------------------------------------------------------------------------
__global__ __launch_bounds__(256) void proj_gemm(const bf16* __restrict__ ain,
                                                 const float* __restrict__ w,
                                                 const float* __restrict__ bp,
                                                 float* __restrict__ out) {
    __shared__ __align__(16) bf16 aT[64][264];
    const int tid  = threadIdx.x;
    const int lane = tid & 63;
    const int wv   = tid >> 6;
    const int wn   = wv & 1, wo = wv >> 1;
    const int l15  = lane & 15, l4 = lane >> 4;
    const int g0 = blockIdx.x * 64;
    const int b  = g0 / NPIX;
    const int n0 = g0 % NPIX;
    const int o0 = blockIdx.y * 64;
    const bf16* ab = ain + (size_t)b * CCH * NPIX;

    // stage whole 64n x 256c tile: pairs of c-rows, 8 n per thread-unit
    {
        const int nq  = (tid & 7) * 8;
        const int cp0 = tid >> 3;            // 0..31
        for (int i = 0; i < 4; ++i) {
            const int c = (i * 32 + cp0) * 2;
            ushort8 a0 = *(const ushort8*)&ab[(size_t)c * NPIX + n0 + nq];
            ushort8 a1 = *(const ushort8*)&ab[(size_t)(c + 1) * NPIX + n0 + nq];
            for (int j = 0; j < 8; ++j) {
                unsigned int u = (unsigned int)a0[j] | ((unsigned int)a1[j] << 16);
                *(unsigned int*)&aT[nq + j][c] = u;
            }
        }
    }
    __syncthreads();

    f32x4 acc[2][2] = {};
    for (int kc = 0; kc < 8; ++kc) {
        bf16x8 afr[2], bfr[2];
        for (int at = 0; at < 2; ++at) {
            const float* wp = w + (size_t)(o0 + wo * 32 + at * 16 + l15) * CCH + kc * 32 + l4 * 8;
            f32x4 w0 = *(const f32x4*)wp;
            f32x4 w1 = *(const f32x4*)(wp + 4);
            bf16x8 a;
            for (int i = 0; i < 4; ++i) { a[i] = (bf16)w0[i]; a[i + 4] = (bf16)w1[i]; }
            afr[at] = a;
        }
        for (int bt = 0; bt < 2; ++bt)
            bfr[bt] = *(const bf16x8*)&aT[wn * 32 + bt * 16 + l15][kc * 32 + l4 * 8];
        for (int at = 0; at < 2; ++at)
            for (int bt = 0; bt < 2; ++bt)
                acc[at][bt] = __builtin_amdgcn_mfma_f32_16x16x32_bf16(afr[at], bfr[bt],
                                                                     acc[at][bt], 0, 0, 0);
    }
    for (int at = 0; at < 2; ++at)
        for (int bt = 0; bt < 2; ++bt) {
            const int n = n0 + wn * 32 + bt * 16 + l15;
            for (int r = 0; r < 4; ++r) {
                const int o = o0 + wo * 32 + at * 16 + l4 * 4 + r;
                out[(size_t)(b * 256 + o) * NPIX + n] = acc[at][bt][r] + bp[o];
            }
        }
}

// ---------------------------------------------------------------------------
extern "C" void kernel_launch(void* const* d_in, const int* in_sizes, int n_in,
                              void* d_out, int out_size, void* d_ws, size_t ws_size,
                              hipStream_t stream) {
    const float* x      = (const float*)d_in[0];
    const float* w_qkv  = (const float*)d_in[1];
    const float* w_lepe = (const float*)d_in[2];
    const float* b_lepe = (const float*)d_in[3];
    const float* w_proj = (const float*)d_in[4];
    const float* b_proj = (const float*)d_in[5];
    float* out = (float*)d_out;

    // ws layout: Qt|Kt|V|aout (bf16, 4 x 1179648 elems = 9.44MB),
    // then Opart fp32 (4*16*2304*32 = 18.9MB), MLpart fp32 (1.2MB)
    bf16* Qt   = (bf16*)d_ws;
    bf16* Kt   = Qt + 1179648;
    bf16* Vb   = Kt + 1179648;
    bf16* aout = Vb + 1179648;
    float* Opart  = (float*)((char*)d_ws + 9437184);
    float* MLpart = Opart + 4718592;

    qkv_gemm      <<<dim3(72, 12),    256, 0, stream>>>(x, w_qkv, Qt, Kt, Vb);
    attn_kernel   <<<dim3(36, 16, 4), 256, 0, stream>>>(Qt, Kt, Vb, Opart, MLpart);
    epilogue_kernel<<<dim3(36, 16),   256, 0, stream>>>(Opart, MLpart, Vb, w_lepe, b_lepe, aout);
    proj_gemm     <<<dim3(72, 4),     256, 0, stream>>>(aout, w_proj, b_proj, out);
}

// Round 15
// 138.069 us; speedup vs baseline: 1.4502x; 1.0516x over previous
//
#include <hip/hip_runtime.h>
#include <hip/hip_bf16.h>

typedef __bf16 bf16;
typedef __bf16 bf16x8 __attribute__((ext_vector_type(8)));
typedef __bf16 bf16x4 __attribute__((ext_vector_type(4)));
typedef __bf16 bf16x2 __attribute__((ext_vector_type(2)));
typedef unsigned short ushort8 __attribute__((ext_vector_type(8)));
typedef float  f32x4  __attribute__((ext_vector_type(4)));
typedef float  f32x2  __attribute__((ext_vector_type(2)));

#define NB    2
#define CCH   256
#define NPIX  2304
#define WIMG  48
// scale * log2(e) = (1/sqrt(32)) * 1.4426950408889634  (folded into Kt)
#define SLOG2E 0.25503487f
#define NSPLIT 4
#define KSEG   576
#define TK     64
#define NITER  9

// ---------------------------------------------------------------------------
// Kernel 1: qkv = w_qkv @ x   (M=768, K=256, cols = B*2304)
// v3: whole-K LDS staging + 128-row o-tile per block (grid y 12->6) so the
// x-tile staging is amortized 2x. Wave layout 1n x 4o; 8 MFMA/kc/wave.
// Qt/Kt as [bh][n][32] bf16 (Kt pre-scaled by scale*log2e), V as [bh][32][n].
// ---------------------------------------------------------------------------
__global__ __launch_bounds__(256) void qkv_gemm(const float* __restrict__ x,
                                                const float* __restrict__ w,
                                                bf16* __restrict__ Qt,
                                                bf16* __restrict__ Kt,
                                                bf16* __restrict__ Vb) {
    __shared__ __align__(16) bf16 xT[64][264];  // [n][c], rows 528B
    const int tid  = threadIdx.x;
    const int lane = tid & 63;
    const int wv   = tid >> 6;           // wave owns o-rows [o0+wv*32, +32)
    const int l15  = lane & 15, l4 = lane >> 4;
    const int g0 = blockIdx.x * 64;
    const int b  = g0 / NPIX;
    const int n0 = g0 % NPIX;
    const int o0 = blockIdx.y * 128;
    const float* xb = x + (size_t)b * CCH * NPIX;

    // stage whole 64n x 256c tile: pairs of c-rows, 4 n per thread-unit
    {
        const int nq  = (tid & 15) * 4;
        const int cp0 = tid >> 4;            // 0..15
        for (int i = 0; i < 8; ++i) {
            const int c = (i * 16 + cp0) * 2;
            f32x4 a0 = *(const f32x4*)&xb[(size_t)c * NPIX + n0 + nq];
            f32x4 a1 = *(const f32x4*)&xb[(size_t)(c + 1) * NPIX + n0 + nq];
            for (int j = 0; j < 4; ++j) {
                bf16x2 p; p[0] = (bf16)a0[j]; p[1] = (bf16)a1[j];
                *(bf16x2*)&xT[nq + j][c] = p;
            }
        }
    }
    __syncthreads();

    f32x4 acc[2][4] = {};
    for (int kc = 0; kc < 8; ++kc) {
        bf16x8 bfr[4];
        for (int bt = 0; bt < 4; ++bt)
            bfr[bt] = *(const bf16x8*)&xT[bt * 16 + l15][kc * 32 + l4 * 8];
        bf16x8 afr[2];
        for (int at = 0; at < 2; ++at) {
            const float* wp = w + (size_t)(o0 + wv * 32 + at * 16 + l15) * CCH + kc * 32 + l4 * 8;
            f32x4 w0 = *(const f32x4*)wp;
            f32x4 w1 = *(const f32x4*)(wp + 4);
            bf16x8 a;
            for (int i = 0; i < 4; ++i) { a[i] = (bf16)w0[i]; a[i + 4] = (bf16)w1[i]; }
            afr[at] = a;
        }
        for (int at = 0; at < 2; ++at)
            for (int bt = 0; bt < 4; ++bt)
                acc[at][bt] = __builtin_amdgcn_mfma_f32_16x16x32_bf16(afr[at], bfr[bt],
                                                                     acc[at][bt], 0, 0, 0);
    }

    for (int at = 0; at < 2; ++at) {
        const int otile = o0 + wv * 32 + at * 16;      // 16-aligned
        const int h    = otile / 96;
        const int role = (otile % 96) / 32;            // 0=q 1=k 2=v
        const int ddb  = (otile % 32) + l4 * 4;
        const int bh   = b * 8 + h;
        for (int bt = 0; bt < 4; ++bt) {
            const int n = n0 + bt * 16 + l15;
            if (role == 2) {
                for (int r = 0; r < 4; ++r)
                    Vb[(size_t)(bh * 32 + ddb + r) * NPIX + n] = (bf16)acc[at][bt][r];
            } else if (role == 1) {
                bf16x4 pk;
                for (int r = 0; r < 4; ++r) pk[r] = (bf16)(acc[at][bt][r] * SLOG2E);
                *(bf16x4*)&Kt[((size_t)bh * NPIX + n) * 32 + ddb] = pk;
            } else {
                bf16x4 pk;
                for (int r = 0; r < 4; ++r) pk[r] = (bf16)acc[at][bt][r];
                *(bf16x4*)&Qt[((size_t)bh * NPIX + n) * 32 + ddb] = pk;
            }
        }
    }
}

// ---------------------------------------------------------------------------
// Kernel 2: flash attention, K-split x4. Grid (36, 16, 4) — unchanged (r12).
// ---------------------------------------------------------------------------
__global__ __launch_bounds__(256, 4) void attn_kernel(const bf16* __restrict__ Qt,
                                                      const bf16* __restrict__ Kt,
                                                      const bf16* __restrict__ Vb,
                                                      float* __restrict__ Opart,
                                                      float* __restrict__ MLpart) {
    __shared__ __align__(16) bf16 Ktile[64][40];    // [k][d]  80B rows
    __shared__ __align__(16) bf16 Vtile[32][72];    // [d][k]  144B rows
    __shared__ __align__(16) bf16 Ptile[64][72];    // [q][k]  wave-private rows
    const int tid  = threadIdx.x;
    const int lane = tid & 63;
    const int wv   = tid >> 6;
    const int l15  = lane & 15, l4 = lane >> 4;
    const int bh    = blockIdx.y;
    const int split = blockIdx.z;
    const int q0 = blockIdx.x * 64;
    const int q  = q0 + wv * 16 + l15;

    const bf16* Kbh = Kt + (size_t)bh * NPIX * 32 + (size_t)split * KSEG * 32;
    const bf16* Vbh = Vb + (size_t)bh * 32 * NPIX + split * KSEG;

    bf16x8 qf = *(const bf16x8*)&Qt[((size_t)bh * NPIX + q) * 32 + l4 * 8];

    const int krow = tid >> 2, kcol = (tid & 3) * 8;
    const int vd   = tid >> 3, vc   = (tid & 7) * 8;
    const bf16* ksrc = Kbh + (size_t)krow * 32 + kcol;
    const bf16* vsrc = Vbh + (size_t)vd * NPIX + vc;

    bf16x8 ka, va;
    ka = *(const bf16x8*)(ksrc);
    va = *(const bf16x8*)(vsrc);
    *(bf16x8*)&Ktile[krow][kcol] = ka;
    *(bf16x8*)&Vtile[vd][vc]     = va;
    __syncthreads();

    f32x4 O0 = {}, O1 = {};
    float m_run = -INFINITY, l_run = 0.f;
    const int qrow = wv * 16 + l15;

    for (int kt = 0; kt < NITER; ++kt) {
        if (kt + 1 < NITER) {
            ka = *(const bf16x8*)(ksrc + (size_t)(kt + 1) * TK * 32);
            va = *(const bf16x8*)(vsrc + (kt + 1) * TK);
        }

        f32x4 s[4];
        for (int rt = 0; rt < 4; ++rt) {
            bf16x8 a = *(const bf16x8*)&Ktile[rt * 16 + l15][l4 * 8];
            f32x4 z = {};
            s[rt] = __builtin_amdgcn_mfma_f32_16x16x32_bf16(a, qf, z, 0, 0, 0);
        }

        float tmax = -INFINITY;
        for (int rt = 0; rt < 4; ++rt)
            for (int r = 0; r < 4; ++r) tmax = fmaxf(tmax, s[rt][r]);
        tmax = fmaxf(tmax, __shfl_xor(tmax, 16));
        tmax = fmaxf(tmax, __shfl_xor(tmax, 32));
        const float m_new = fmaxf(m_run, tmax);
        const float f = __builtin_amdgcn_exp2f(m_run - m_new);
        float psum = 0.f;
        for (int rt = 0; rt < 4; ++rt) {
            bf16x4 pk;
            for (int r = 0; r < 4; ++r) {
                float p = __builtin_amdgcn_exp2f(s[rt][r] - m_new);
                psum += p;
                pk[r] = (bf16)p;
            }
            *(bf16x4*)&Ptile[qrow][rt * 16 + l4 * 4] = pk;
        }
        psum += __shfl_xor(psum, 16);
        psum += __shfl_xor(psum, 32);
        l_run = l_run * f + psum;
        m_run = m_new;
        for (int i = 0; i < 4; ++i) { O0[i] *= f; O1[i] *= f; }

        for (int ks = 0; ks < 2; ++ks) {
            bf16x8 pb = *(const bf16x8*)&Ptile[qrow][ks * 32 + l4 * 8];
            bf16x8 v0 = *(const bf16x8*)&Vtile[l15][ks * 32 + l4 * 8];
            bf16x8 v1 = *(const bf16x8*)&Vtile[16 + l15][ks * 32 + l4 * 8];
            O0 = __builtin_amdgcn_mfma_f32_16x16x32_bf16(v0, pb, O0, 0, 0, 0);
            O1 = __builtin_amdgcn_mfma_f32_16x16x32_bf16(v1, pb, O1, 0, 0, 0);
        }
        __syncthreads();
        if (kt + 1 < NITER) {
            *(bf16x8*)&Ktile[krow][kcol] = ka;
            *(bf16x8*)&Vtile[vd][vc]     = va;
        }
        __syncthreads();
    }

    f32x4* Op4 = (f32x4*)(Opart + ((size_t)(split * 16 + bh) * NPIX + q) * 32);
    Op4[l4]     = O0;
    Op4[4 + l4] = O1;
    if (l4 == 0) {
        f32x2 ml; ml[0] = m_run; ml[1] = l_run;
        *(f32x2*)&MLpart[((size_t)(split * 16 + bh) * NPIX + q) * 2] = ml;
    }
}

// ---------------------------------------------------------------------------
// Kernel 2b: fused epilogue — combine 4 K-split partials + lepe — unchanged.
// ---------------------------------------------------------------------------
__global__ __launch_bounds__(256) void epilogue_kernel(const float* __restrict__ Opart,
                                                       const float* __restrict__ MLpart,
                                                       const bf16* __restrict__ Vb,
                                                       const float* __restrict__ wl,
                                                       const float* __restrict__ bl,
                                                       bf16* __restrict__ aout) {
    __shared__ float wnorm[NSPLIT][72];
    __shared__ float vals[32][69];
    const int tid = threadIdx.x;
    const int bh  = blockIdx.y;
    const int q0  = blockIdx.x * 64;

    if (tid < 64) {
        const int q = q0 + tid;
        float mv[NSPLIT], lv[NSPLIT], m = -INFINITY;
        for (int s = 0; s < NSPLIT; ++s) {
            f32x2 ml = *(const f32x2*)&MLpart[((size_t)(s * 16 + bh) * NPIX + q) * 2];
            mv[s] = ml[0]; lv[s] = ml[1];
            m = fmaxf(m, ml[0]);
        }
        float wsv[NSPLIT], denom = 0.f;
        for (int s = 0; s < NSPLIT; ++s) {
            wsv[s] = __builtin_amdgcn_exp2f(mv[s] - m);
            denom += wsv[s] * lv[s];
        }
        const float inv = 1.f / denom;
        for (int s = 0; s < NSPLIT; ++s) wnorm[s][tid] = wsv[s] * inv;
    }
    __syncthreads();

    {
        const int d  = tid & 31;
        const int qg = tid >> 5;
        for (int j = 0; j < 8; ++j) {
            const int qq = qg * 8 + j;
            const int q  = q0 + qq;
            float v = 0.f;
            for (int s = 0; s < NSPLIT; ++s)
                v += wnorm[s][qq] * Opart[((size_t)(s * 16 + bh) * NPIX + q) * 32 + d];
            vals[d][qq] = v;
        }
    }
    __syncthreads();

    const int d2 = tid >> 3;
    const int n8 = (tid & 7) * 8;
    const int c  = bh * 32 + d2;
    const int ch = c & 255;
    const float bias = bl[ch];
    float wgt[9];
    for (int i = 0; i < 9; ++i) wgt[i] = wl[ch * 9 + i];
    const bf16* vrow = Vb + (size_t)c * NPIX;

    for (int j = 0; j < 8; ++j) {
        const int q = q0 + n8 + j;
        float val = vals[d2][n8 + j];
        const int y = q / WIMG, xx = q % WIMG;
        float acc = bias;
        for (int dy = -1; dy <= 1; ++dy) {
            const int yy = y + dy;
            if (yy < 0 || yy >= WIMG) continue;
            for (int dx = -1; dx <= 1; ++dx) {
                const int xc = xx + dx;
                if (xc < 0 || xc >= WIMG) continue;
                acc += (float)vrow[yy * WIMG + xc] * wgt[(dy + 1) * 3 + dx + 1];
            }
        }
        aout[(size_t)c * NPIX + q] = (bf16)(val + acc);
    }
}

// ---------------------------------------------------------------------------
// Kernel 4: out = w_proj @ attn_out + b_proj  (fp32 output) — unchanged (r14).
// ---------------------------------------------------------------------------
__global__ __launch_bounds__(256) void proj_gemm(const bf16* __restrict__ ain,
                                                 const float* __restrict__ w,
                                                 const float* __restrict__ bp,
                                                 float* __restrict__ out) {
    __shared__ __align__(16) bf16 aT[64][264];
    const int tid  = threadIdx.x;
    const int lane = tid & 63;
    const int wv   = tid >> 6;
    const int wn   = wv & 1, wo = wv >> 1;
    const int l15  = lane & 15, l4 = lane >> 4;
    const int g0 = blockIdx.x * 64;
    const int b  = g0 / NPIX;
    const int n0 = g0 % NPIX;
    const int o0 = blockIdx.y * 64;
    const bf16* ab = ain + (size_t)b * CCH * NPIX;

    // stage whole 64n x 256c tile: pairs of c-rows, 8 n per thread-unit
    {
        const int nq  = (tid & 7) * 8;
        const int cp0 = tid >> 3;            // 0..31
        for (int i = 0; i < 4; ++i) {
            const int c = (i * 32 + cp0) * 2;
            ushort8 a0 = *(const ushort8*)&ab[(size_t)c * NPIX + n0 + nq];
            ushort8 a1 = *(const ushort8*)&ab[(size_t)(c + 1) * NPIX + n0 + nq];
            for (int j = 0; j < 8; ++j) {
                unsigned int u = (unsigned int)a0[j] | ((unsigned int)a1[j] << 16);
                *(unsigned int*)&aT[nq + j][c] = u;
            }
        }
    }
    __syncthreads();

    f32x4 acc[2][2] = {};
    for (int kc = 0; kc < 8; ++kc) {
        bf16x8 afr[2], bfr[2];
        for (int at = 0; at < 2; ++at) {
            const float* wp = w + (size_t)(o0 + wo * 32 + at * 16 + l15) * CCH + kc * 32 + l4 * 8;
            f32x4 w0 = *(const f32x4*)wp;
            f32x4 w1 = *(const f32x4*)(wp + 4);
            bf16x8 a;
            for (int i = 0; i < 4; ++i) { a[i] = (bf16)w0[i]; a[i + 4] = (bf16)w1[i]; }
            afr[at] = a;
        }
        for (int bt = 0; bt < 2; ++bt)
            bfr[bt] = *(const bf16x8*)&aT[wn * 32 + bt * 16 + l15][kc * 32 + l4 * 8];
        for (int at = 0; at < 2; ++at)
            for (int bt = 0; bt < 2; ++bt)
                acc[at][bt] = __builtin_amdgcn_mfma_f32_16x16x32_bf16(afr[at], bfr[bt],
                                                                     acc[at][bt], 0, 0, 0);
    }
    for (int at = 0; at < 2; ++at)
        for (int bt = 0; bt < 2; ++bt) {
            const int n = n0 + wn * 32 + bt * 16 + l15;
            for (int r = 0; r < 4; ++r) {
                const int o = o0 + wo * 32 + at * 16 + l4 * 4 + r;
                out[(size_t)(b * 256 + o) * NPIX + n] = acc[at][bt][r] + bp[o];
            }
        }
}

// ---------------------------------------------------------------------------
extern "C" void kernel_launch(void* const* d_in, const int* in_sizes, int n_in,
                              void* d_out, int out_size, void* d_ws, size_t ws_size,
                              hipStream_t stream) {
    const float* x      = (const float*)d_in[0];
    const float* w_qkv  = (const float*)d_in[1];
    const float* w_lepe = (const float*)d_in[2];
    const float* b_lepe = (const float*)d_in[3];
    const float* w_proj = (const float*)d_in[4];
    const float* b_proj = (const float*)d_in[5];
    float* out = (float*)d_out;

    // ws layout: Qt|Kt|V|aout (bf16, 4 x 1179648 elems = 9.44MB),
    // then Opart fp32 (4*16*2304*32 = 18.9MB), MLpart fp32 (1.2MB)
    bf16* Qt   = (bf16*)d_ws;
    bf16* Kt   = Qt + 1179648;
    bf16* Vb   = Kt + 1179648;
    bf16* aout = Vb + 1179648;
    float* Opart  = (float*)((char*)d_ws + 9437184);
    float* MLpart = Opart + 4718592;

    qkv_gemm      <<<dim3(72, 6),     256, 0, stream>>>(x, w_qkv, Qt, Kt, Vb);
    attn_kernel   <<<dim3(36, 16, 4), 256, 0, stream>>>(Qt, Kt, Vb, Opart, MLpart);
    epilogue_kernel<<<dim3(36, 16),   256, 0, stream>>>(Opart, MLpart, Vb, w_lepe, b_lepe, aout);
    proj_gemm     <<<dim3(72, 4),     256, 0, stream>>>(aout, w_proj, b_proj, out);
}

// Round 17
// 137.270 us; speedup vs baseline: 1.4587x; 1.0058x over previous
//
#include <hip/hip_runtime.h>
#include <hip/hip_bf16.h>

typedef __bf16 bf16;
typedef __bf16 bf16x8 __attribute__((ext_vector_type(8)));
typedef __bf16 bf16x4 __attribute__((ext_vector_type(4)));
typedef __bf16 bf16x2 __attribute__((ext_vector_type(2)));
typedef unsigned short ushort8 __attribute__((ext_vector_type(8)));
typedef float  f32x4  __attribute__((ext_vector_type(4)));
typedef float  f32x2  __attribute__((ext_vector_type(2)));

#define NB    2
#define CCH   256
#define NPIX  2304
#define WIMG  48
// scale * log2(e) = (1/sqrt(32)) * 1.4426950408889634  (folded into Kt)
#define SLOG2E 0.25503487f
#define NSPLIT 4
#define KSEG   576
#define TK     64
#define NITER  9

// ---------------------------------------------------------------------------
// Kernel 1: qkv = w_qkv @ x   (M=768, K=256, cols = B*2304)
// v4: 512-thread blocks, 256-row o-tile (grid y 3) — staging amortized 4x
// vs v2. 8 waves, each owns 32 o-rows; per-wave MFMA code unchanged.
// ---------------------------------------------------------------------------
__global__ __launch_bounds__(512) void qkv_gemm(const float* __restrict__ x,
                                                const float* __restrict__ w,
                                                bf16* __restrict__ Qt,
                                                bf16* __restrict__ Kt,
                                                bf16* __restrict__ Vb) {
    __shared__ __align__(16) bf16 xT[64][264];  // [n][c], rows 528B
    const int tid  = threadIdx.x;
    const int lane = tid & 63;
    const int wv   = tid >> 6;           // 0..7, wave owns o-rows o0+wv*32..+32
    const int l15  = lane & 15, l4 = lane >> 4;
    const int g0 = blockIdx.x * 64;
    const int b  = g0 / NPIX;
    const int n0 = g0 % NPIX;
    const int o0 = blockIdx.y * 256;
    const float* xb = x + (size_t)b * CCH * NPIX;

    // stage whole 64n x 256c tile: pairs of c-rows, 4 n per thread-unit
    {
        const int nq  = (tid & 15) * 4;
        const int cp0 = tid >> 4;            // 0..31
        for (int i = 0; i < 4; ++i) {
            const int c = (i * 32 + cp0) * 2;
            f32x4 a0 = *(const f32x4*)&xb[(size_t)c * NPIX + n0 + nq];
            f32x4 a1 = *(const f32x4*)&xb[(size_t)(c + 1) * NPIX + n0 + nq];
            for (int j = 0; j < 4; ++j) {
                bf16x2 p; p[0] = (bf16)a0[j]; p[1] = (bf16)a1[j];
                *(bf16x2*)&xT[nq + j][c] = p;
            }
        }
    }
    __syncthreads();

    f32x4 acc[2][4] = {};
    for (int kc = 0; kc < 8; ++kc) {
        bf16x8 bfr[4];
        for (int bt = 0; bt < 4; ++bt)
            bfr[bt] = *(const bf16x8*)&xT[bt * 16 + l15][kc * 32 + l4 * 8];
        bf16x8 afr[2];
        for (int at = 0; at < 2; ++at) {
            const float* wp = w + (size_t)(o0 + wv * 32 + at * 16 + l15) * CCH + kc * 32 + l4 * 8;
            f32x4 w0 = *(const f32x4*)wp;
            f32x4 w1 = *(const f32x4*)(wp + 4);
            bf16x8 a;
            for (int i = 0; i < 4; ++i) { a[i] = (bf16)w0[i]; a[i + 4] = (bf16)w1[i]; }
            afr[at] = a;
        }
        for (int at = 0; at < 2; ++at)
            for (int bt = 0; bt < 4; ++bt)
                acc[at][bt] = __builtin_amdgcn_mfma_f32_16x16x32_bf16(afr[at], bfr[bt],
                                                                     acc[at][bt], 0, 0, 0);
    }

    for (int at = 0; at < 2; ++at) {
        const int otile = o0 + wv * 32 + at * 16;      // 16-aligned
        const int h    = otile / 96;
        const int role = (otile % 96) / 32;            // 0=q 1=k 2=v
        const int ddb  = (otile % 32) + l4 * 4;
        const int bh   = b * 8 + h;
        for (int bt = 0; bt < 4; ++bt) {
            const int n = n0 + bt * 16 + l15;
            if (role == 2) {
                for (int r = 0; r < 4; ++r)
                    Vb[(size_t)(bh * 32 + ddb + r) * NPIX + n] = (bf16)acc[at][bt][r];
            } else if (role == 1) {
                bf16x4 pk;
                for (int r = 0; r < 4; ++r) pk[r] = (bf16)(acc[at][bt][r] * SLOG2E);
                *(bf16x4*)&Kt[((size_t)bh * NPIX + n) * 32 + ddb] = pk;
            } else {
                bf16x4 pk;
                for (int r = 0; r < 4; ++r) pk[r] = (bf16)acc[at][bt][r];
                *(bf16x4*)&Qt[((size_t)bh * NPIX + n) * 32 + ddb] = pk;
            }
        }
    }
}

// ---------------------------------------------------------------------------
// Kernel 2: flash attention, K-split x4. Grid (36, 16, 4) — unchanged (r12).
// ---------------------------------------------------------------------------
__global__ __launch_bounds__(256, 4) void attn_kernel(const bf16* __restrict__ Qt,
                                                      const bf16* __restrict__ Kt,
                                                      const bf16* __restrict__ Vb,
                                                      float* __restrict__ Opart,
                                                      float* __restrict__ MLpart) {
    __shared__ __align__(16) bf16 Ktile[64][40];    // [k][d]  80B rows
    __shared__ __align__(16) bf16 Vtile[32][72];    // [d][k]  144B rows
    __shared__ __align__(16) bf16 Ptile[64][72];    // [q][k]  wave-private rows
    const int tid  = threadIdx.x;
    const int lane = tid & 63;
    const int wv   = tid >> 6;
    const int l15  = lane & 15, l4 = lane >> 4;
    const int bh    = blockIdx.y;
    const int split = blockIdx.z;
    const int q0 = blockIdx.x * 64;
    const int q  = q0 + wv * 16 + l15;

    const bf16* Kbh = Kt + (size_t)bh * NPIX * 32 + (size_t)split * KSEG * 32;
    const bf16* Vbh = Vb + (size_t)bh * 32 * NPIX + split * KSEG;

    bf16x8 qf = *(const bf16x8*)&Qt[((size_t)bh * NPIX + q) * 32 + l4 * 8];

    const int krow = tid >> 2, kcol = (tid & 3) * 8;
    const int vd   = tid >> 3, vc   = (tid & 7) * 8;
    const bf16* ksrc = Kbh + (size_t)krow * 32 + kcol;
    const bf16* vsrc = Vbh + (size_t)vd * NPIX + vc;

    bf16x8 ka, va;
    ka = *(const bf16x8*)(ksrc);
    va = *(const bf16x8*)(vsrc);
    *(bf16x8*)&Ktile[krow][kcol] = ka;
    *(bf16x8*)&Vtile[vd][vc]     = va;
    __syncthreads();

    f32x4 O0 = {}, O1 = {};
    float m_run = -INFINITY, l_run = 0.f;
    const int qrow = wv * 16 + l15;

    for (int kt = 0; kt < NITER; ++kt) {
        if (kt + 1 < NITER) {
            ka = *(const bf16x8*)(ksrc + (size_t)(kt + 1) * TK * 32);
            va = *(const bf16x8*)(vsrc + (kt + 1) * TK);
        }

        f32x4 s[4];
        for (int rt = 0; rt < 4; ++rt) {
            bf16x8 a = *(const bf16x8*)&Ktile[rt * 16 + l15][l4 * 8];
            f32x4 z = {};
            s[rt] = __builtin_amdgcn_mfma_f32_16x16x32_bf16(a, qf, z, 0, 0, 0);
        }

        float tmax = -INFINITY;
        for (int rt = 0; rt < 4; ++rt)
            for (int r = 0; r < 4; ++r) tmax = fmaxf(tmax, s[rt][r]);
        tmax = fmaxf(tmax, __shfl_xor(tmax, 16));
        tmax = fmaxf(tmax, __shfl_xor(tmax, 32));
        const float m_new = fmaxf(m_run, tmax);
        const float f = __builtin_amdgcn_exp2f(m_run - m_new);
        float psum = 0.f;
        for (int rt = 0; rt < 4; ++rt) {
            bf16x4 pk;
            for (int r = 0; r < 4; ++r) {
                float p = __builtin_amdgcn_exp2f(s[rt][r] - m_new);
                psum += p;
                pk[r] = (bf16)p;
            }
            *(bf16x4*)&Ptile[qrow][rt * 16 + l4 * 4] = pk;
        }
        psum += __shfl_xor(psum, 16);
        psum += __shfl_xor(psum, 32);
        l_run = l_run * f + psum;
        m_run = m_new;
        for (int i = 0; i < 4; ++i) { O0[i] *= f; O1[i] *= f; }

        for (int ks = 0; ks < 2; ++ks) {
            bf16x8 pb = *(const bf16x8*)&Ptile[qrow][ks * 32 + l4 * 8];
            bf16x8 v0 = *(const bf16x8*)&Vtile[l15][ks * 32 + l4 * 8];
            bf16x8 v1 = *(const bf16x8*)&Vtile[16 + l15][ks * 32 + l4 * 8];
            O0 = __builtin_amdgcn_mfma_f32_16x16x32_bf16(v0, pb, O0, 0, 0, 0);
            O1 = __builtin_amdgcn_mfma_f32_16x16x32_bf16(v1, pb, O1, 0, 0, 0);
        }
        __syncthreads();
        if (kt + 1 < NITER) {
            *(bf16x8*)&Ktile[krow][kcol] = ka;
            *(bf16x8*)&Vtile[vd][vc]     = va;
        }
        __syncthreads();
    }

    f32x4* Op4 = (f32x4*)(Opart + ((size_t)(split * 16 + bh) * NPIX + q) * 32);
    Op4[l4]     = O0;
    Op4[4 + l4] = O1;
    if (l4 == 0) {
        f32x2 ml; ml[0] = m_run; ml[1] = l_run;
        *(f32x2*)&MLpart[((size_t)(split * 16 + bh) * NPIX + q) * 2] = ml;
    }
}

// ---------------------------------------------------------------------------
// Kernel 2b: fused epilogue — combine 4 K-split partials + lepe — unchanged.
// ---------------------------------------------------------------------------
__global__ __launch_bounds__(256) void epilogue_kernel(const float* __restrict__ Opart,
                                                       const float* __restrict__ MLpart,
                                                       const bf16* __restrict__ Vb,
                                                       const float* __restrict__ wl,
                                                       const float* __restrict__ bl,
                                                       bf16* __restrict__ aout) {
    __shared__ float wnorm[NSPLIT][72];
    __shared__ float vals[32][69];
    const int tid = threadIdx.x;
    const int bh  = blockIdx.y;
    const int q0  = blockIdx.x * 64;

    if (tid < 64) {
        const int q = q0 + tid;
        float mv[NSPLIT], lv[NSPLIT], m = -INFINITY;
        for (int s = 0; s < NSPLIT; ++s) {
            f32x2 ml = *(const f32x2*)&MLpart[((size_t)(s * 16 + bh) * NPIX + q) * 2];
            mv[s] = ml[0]; lv[s] = ml[1];
            m = fmaxf(m, ml[0]);
        }
        float wsv[NSPLIT], denom = 0.f;
        for (int s = 0; s < NSPLIT; ++s) {
            wsv[s] = __builtin_amdgcn_exp2f(mv[s] - m);
            denom += wsv[s] * lv[s];
        }
        const float inv = 1.f / denom;
        for (int s = 0; s < NSPLIT; ++s) wnorm[s][tid] = wsv[s] * inv;
    }
    __syncthreads();

    {
        const int d  = tid & 31;
        const int qg = tid >> 5;
        for (int j = 0; j < 8; ++j) {
            const int qq = qg * 8 + j;
            const int q  = q0 + qq;
            float v = 0.f;
            for (int s = 0; s < NSPLIT; ++s)
                v += wnorm[s][qq] * Opart[((size_t)(s * 16 + bh) * NPIX + q) * 32 + d];
            vals[d][qq] = v;
        }
    }
    __syncthreads();

    const int d2 = tid >> 3;
    const int n8 = (tid & 7) * 8;
    const int c  = bh * 32 + d2;
    const int ch = c & 255;
    const float bias = bl[ch];
    float wgt[9];
    for (int i = 0; i < 9; ++i) wgt[i] = wl[ch * 9 + i];
    const bf16* vrow = Vb + (size_t)c * NPIX;

    for (int j = 0; j < 8; ++j) {
        const int q = q0 + n8 + j;
        float val = vals[d2][n8 + j];
        const int y = q / WIMG, xx = q % WIMG;
        float acc = bias;
        for (int dy = -1; dy <= 1; ++dy) {
            const int yy = y + dy;
            if (yy < 0 || yy >= WIMG) continue;
            for (int dx = -1; dx <= 1; ++dx) {
                const int xc = xx + dx;
                if (xc < 0 || xc >= WIMG) continue;
                acc += (float)vrow[yy * WIMG + xc] * wgt[(dy + 1) * 3 + dx + 1];
            }
        }
        aout[(size_t)c * NPIX + q] = (bf16)(val + acc);
    }
}

// ---------------------------------------------------------------------------
// Kernel 4: out = w_proj @ attn_out + b_proj  (fp32 output)
// v3: 512-thread blocks, 128-row o-tile (grid y 2) — staging amortized 2x.
// 8 waves in 2n x 4o layout; per-wave code identical to v2.
// ---------------------------------------------------------------------------
__global__ __launch_bounds__(512) void proj_gemm(const bf16* __restrict__ ain,
                                                 const float* __restrict__ w,
                                                 const float* __restrict__ bp,
                                                 float* __restrict__ out) {
    __shared__ __align__(16) bf16 aT[64][264];
    const int tid  = threadIdx.x;
    const int lane = tid & 63;
    const int wv   = tid >> 6;           // 0..7
    const int wn   = wv & 1, wo = wv >> 1;   // 2n x 4o
    const int l15  = lane & 15, l4 = lane >> 4;
    const int g0 = blockIdx.x * 64;
    const int b  = g0 / NPIX;
    const int n0 = g0 % NPIX;
    const int o0 = blockIdx.y * 128;
    const bf16* ab = ain + (size_t)b * CCH * NPIX;

    // stage whole 64n x 256c tile: pairs of c-rows, 8 n per thread-unit
    {
        const int nq  = (tid & 7) * 8;
        const int cp0 = tid >> 3;            // 0..63
        for (int i = 0; i < 2; ++i) {
            const int c = (i * 64 + cp0) * 2;
            ushort8 a0 = *(const ushort8*)&ab[(size_t)c * NPIX + n0 + nq];
            ushort8 a1 = *(const ushort8*)&ab[(size_t)(c + 1) * NPIX + n0 + nq];
            for (int j = 0; j < 8; ++j) {
                unsigned int u = (unsigned int)a0[j] | ((unsigned int)a1[j] << 16);
                *(unsigned int*)&aT[nq + j][c] = u;
            }
        }
    }
    __syncthreads();

    f32x4 acc[2][2] = {};
    for (int kc = 0; kc < 8; ++kc) {
        bf16x8 afr[2], bfr[2];
        for (int at = 0; at < 2; ++at) {
            const float* wp = w + (size_t)(o0 + wo * 32 + at * 16 + l15) * CCH + kc * 32 + l4 * 8;
            f32x4 w0 = *(const f32x4*)wp;
            f32x4 w1 = *(const f32x4*)(wp + 4);
            bf16x8 a;
            for (int i = 0; i < 4; ++i) { a[i] = (bf16)w0[i]; a[i + 4] = (bf16)w1[i]; }
            afr[at] = a;
        }
        for (int bt = 0; bt < 2; ++bt)
            bfr[bt] = *(const bf16x8*)&aT[wn * 32 + bt * 16 + l15][kc * 32 + l4 * 8];
        for (int at = 0; at < 2; ++at)
            for (int bt = 0; bt < 2; ++bt)
                acc[at][bt] = __builtin_amdgcn_mfma_f32_16x16x32_bf16(afr[at], bfr[bt],
                                                                     acc[at][bt], 0, 0, 0);
    }
    for (int at = 0; at < 2; ++at)
        for (int bt = 0; bt < 2; ++bt) {
            const int n = n0 + wn * 32 + bt * 16 + l15;
            for (int r = 0; r < 4; ++r) {
                const int o = o0 + wo * 32 + at * 16 + l4 * 4 + r;
                out[(size_t)(b * 256 + o) * NPIX + n] = acc[at][bt][r] + bp[o];
            }
        }
}

// ---------------------------------------------------------------------------
extern "C" void kernel_launch(void* const* d_in, const int* in_sizes, int n_in,
                              void* d_out, int out_size, void* d_ws, size_t ws_size,
                              hipStream_t stream) {
    const float* x      = (const float*)d_in[0];
    const float* w_qkv  = (const float*)d_in[1];
    const float* w_lepe = (const float*)d_in[2];
    const float* b_lepe = (const float*)d_in[3];
    const float* w_proj = (const float*)d_in[4];
    const float* b_proj = (const float*)d_in[5];
    float* out = (float*)d_out;

    // ws layout: Qt|Kt|V|aout (bf16, 4 x 1179648 elems = 9.44MB),
    // then Opart fp32 (4*16*2304*32 = 18.9MB), MLpart fp32 (1.2MB)
    bf16* Qt   = (bf16*)d_ws;
    bf16* Kt   = Qt + 1179648;
    bf16* Vb   = Kt + 1179648;
    bf16* aout = Vb + 1179648;
    float* Opart  = (float*)((char*)d_ws + 9437184);
    float* MLpart = Opart + 4718592;

    qkv_gemm      <<<dim3(72, 3),     512, 0, stream>>>(x, w_qkv, Qt, Kt, Vb);
    attn_kernel   <<<dim3(36, 16, 4), 256, 0, stream>>>(Qt, Kt, Vb, Opart, MLpart);
    epilogue_kernel<<<dim3(36, 16),   256, 0, stream>>>(Opart, MLpart, Vb, w_lepe, b_lepe, aout);
    proj_gemm     <<<dim3(72, 2),     512, 0, stream>>>(aout, w_proj, b_proj, out);
}